// Round 1
// baseline (195.477 us; speedup 1.0000x reference)
//
#include <hip/hip_runtime.h>

typedef short bf16x8 __attribute__((ext_vector_type(8)));
typedef float f32x4 __attribute__((ext_vector_type(4)));

#define MFMA16(A, B, C) __builtin_amdgcn_mfma_f32_16x16x32_bf16((A), (B), (C), 0, 0, 0)

static constexpr int NB = 4;       // batch
static constexpr int CC = 256;     // channels (INC1 == INC2)
static constexpr int NN = 4096;    // H*W
static constexpr int DD = 64;      // head dim

__device__ __forceinline__ unsigned short f2bf(float f) {
  unsigned int u = __builtin_bit_cast(unsigned int, f);
  u += 0x7fffu + ((u >> 16) & 1u);
  return (unsigned short)(u >> 16);
}

// ---------------------------------------------------------------------------
// Kernel 1: fold BN into projection weights, bf16-cast weights, build biases.
// block 0: kq1 (bn1)  block 1: kq2 (bn2)  block 2: v (raw)  block 3: out (bnl+w_scale)
// ---------------------------------------------------------------------------
__global__ void prep_kernel(
    const float* __restrict__ kq1_w, const float* __restrict__ kq1_b,
    const float* __restrict__ kq2_w, const float* __restrict__ kq2_b,
    const float* __restrict__ v_w,   const float* __restrict__ v_b,
    const float* __restrict__ out_w, const float* __restrict__ out_b,
    const float* __restrict__ bn1_g, const float* __restrict__ bn1_b,
    const float* __restrict__ bn1_m, const float* __restrict__ bn1_v,
    const float* __restrict__ bn2_g, const float* __restrict__ bn2_b,
    const float* __restrict__ bn2_m, const float* __restrict__ bn2_v,
    const float* __restrict__ bnl_g, const float* __restrict__ bnl_b,
    const float* __restrict__ bnl_m, const float* __restrict__ bnl_v,
    const float* __restrict__ w_scale,
    unsigned short* __restrict__ W1, unsigned short* __restrict__ W2,
    unsigned short* __restrict__ WV, unsigned short* __restrict__ WO,
    float* __restrict__ B1, float* __restrict__ B2,
    float* __restrict__ BV, float* __restrict__ BO)
{
  int blk = blockIdx.x;
  int t = threadIdx.x;
  if (blk == 0) {
    if (t < 128) {
      float acc = kq1_b[t];
      for (int c = 0; c < CC; ++c) {
        float s = bn1_g[c] * rsqrtf(bn1_v[c] + 1e-5f);
        float off = bn1_b[c] - bn1_m[c] * s;
        W1[t * CC + c] = f2bf(kq1_w[t * CC + c] * s);
        acc += kq1_w[t * CC + c] * off;
      }
      B1[t] = acc;
    }
  } else if (blk == 1) {
    if (t < 128) {
      float acc = kq2_b[t];
      for (int c = 0; c < CC; ++c) {
        float s = bn2_g[c] * rsqrtf(bn2_v[c] + 1e-5f);
        float off = bn2_b[c] - bn2_m[c] * s;
        W2[t * CC + c] = f2bf(kq2_w[t * CC + c] * s);
        acc += kq2_w[t * CC + c] * off;
      }
      B2[t] = acc;
    }
  } else if (blk == 2) {
    if (t < 128) {
      for (int c = 0; c < CC; ++c) WV[t * CC + c] = f2bf(v_w[t * CC + c]);
      BV[t] = v_b[t];
    }
  } else {
    // t in [0,256): output channel
    float s = bnl_g[t] * rsqrtf(bnl_v[t] + 1e-5f);
    float ws = w_scale[0];
    for (int d = 0; d < 128; ++d) WO[t * 128 + d] = f2bf(ws * s * out_w[t * 128 + d]);
    BO[t] = ws * (out_b[t] * s + bnl_b[t] - bnl_m[t] * s);
  }
}

// ---------------------------------------------------------------------------
// Kernel 2: NCHW f32 -> (b, n, c) bf16 transpose-cast via LDS 64x64 tiles.
// z = tensor*4 + b ; y = c-tile(4) ; x = n-tile(64)
// ---------------------------------------------------------------------------
__global__ __launch_bounds__(256) void conv_kernel(
    const float* __restrict__ x, const float* __restrict__ x1, const float* __restrict__ x2,
    unsigned short* __restrict__ t0, unsigned short* __restrict__ t1, unsigned short* __restrict__ t2)
{
  int tensor = blockIdx.z >> 2, b = blockIdx.z & 3;
  const float* src = tensor == 0 ? x : (tensor == 1 ? x1 : x2);
  unsigned short* dst = tensor == 0 ? t0 : (tensor == 1 ? t1 : t2);
  int cb = blockIdx.y * 64, nb = blockIdx.x * 64;
  __shared__ float tile[64][65];
  int t = threadIdx.x;
  int cl = t >> 2, n0 = (t & 3) * 16;
  const float* s = src + ((size_t)b * CC + cb + cl) * NN + nb + n0;
  f32x4 v0 = *(const f32x4*)(s);
  f32x4 v1 = *(const f32x4*)(s + 4);
  f32x4 v2 = *(const f32x4*)(s + 8);
  f32x4 v3 = *(const f32x4*)(s + 12);
#pragma unroll
  for (int j = 0; j < 4; ++j) {
    tile[cl][n0 + j] = v0[j];
    tile[cl][n0 + 4 + j] = v1[j];
    tile[cl][n0 + 8 + j] = v2[j];
    tile[cl][n0 + 12 + j] = v3[j];
  }
  __syncthreads();
  int nl = t >> 2, c0 = (t & 3) * 16;
  unsigned short* d = dst + ((size_t)b * NN + nb + nl) * CC + cb + c0;
  alignas(16) unsigned short tmp[16];
#pragma unroll
  for (int j = 0; j < 16; ++j) tmp[j] = f2bf(tile[c0 + j][nl]);
  *(bf16x8*)(d) = *(const bf16x8*)(tmp);
  *(bf16x8*)(d + 8) = *(const bf16x8*)(tmp + 8);
}

// ---------------------------------------------------------------------------
// Kernel 3: projections. C(128 x 64n) = Weff(128x256) @ Xt(n,256)^T per (b,mat).
// mat 0 -> kq1 (writes K/Q halves d in [0,32)), mat 1 -> kq2 (d in [32,64)),
// mat 2 -> v (writes Vt (d,n)).
// Q is pre-scaled by 1/sqrt(64)=0.125.
// ---------------------------------------------------------------------------
__global__ __launch_bounds__(256) void proj_kernel(
    const unsigned short* __restrict__ Xt0, const unsigned short* __restrict__ Xt1,
    const unsigned short* __restrict__ Xt2,
    const unsigned short* __restrict__ W1, const unsigned short* __restrict__ W2,
    const unsigned short* __restrict__ WV,
    const float* __restrict__ B1, const float* __restrict__ B2, const float* __restrict__ BV,
    unsigned short* __restrict__ Qb, unsigned short* __restrict__ Kb,
    unsigned short* __restrict__ Vt)
{
  int nt = blockIdx.x;   // n tile (64 wide)
  int mat = blockIdx.y;  // 0..2
  int b = blockIdx.z;
  const unsigned short* X =
      (mat == 0 ? Xt1 : (mat == 1 ? Xt2 : Xt0)) + (size_t)b * NN * CC;
  const unsigned short* W = mat == 0 ? W1 : (mat == 1 ? W2 : WV);
  const float* Bi = mat == 0 ? B1 : (mat == 1 ? B2 : BV);
  int w = threadIdx.x >> 6, lane = threadIdx.x & 63;
  int lhi = lane >> 4, llo = lane & 15;
  int ob = w * 32;

  f32x4 acc[2][4] = {};
#pragma unroll
  for (int kc = 0; kc < 8; ++kc) {
    bf16x8 af[2], bfr[4];
#pragma unroll
    for (int ot = 0; ot < 2; ++ot)
      af[ot] = *(const bf16x8*)(W + (size_t)(ob + ot * 16 + llo) * CC + kc * 32 + lhi * 8);
#pragma unroll
    for (int nn = 0; nn < 4; ++nn)
      bfr[nn] = *(const bf16x8*)(X + ((size_t)nt * 64 + nn * 16 + llo) * CC + kc * 32 + lhi * 8);
#pragma unroll
    for (int ot = 0; ot < 2; ++ot)
#pragma unroll
      for (int nn = 0; nn < 4; ++nn)
        acc[ot][nn] = MFMA16(af[ot], bfr[nn], acc[ot][nn]);
  }

#pragma unroll
  for (int ot = 0; ot < 2; ++ot)
#pragma unroll
    for (int nn = 0; nn < 4; ++nn)
#pragma unroll
      for (int r = 0; r < 4; ++r) {
        int o = ob + ot * 16 + lhi * 4 + r;
        int n = nt * 64 + nn * 16 + llo;
        float val = acc[ot][nn][r] + Bi[o];
        if (mat < 2) {
          int blk = o >> 5;              // 0:K a0  1:Q a0  2:K a1  3:Q a1
          int aa = blk >> 1;
          int d = (o & 31) + mat * 32;
          if (blk & 1) val *= 0.125f;
          unsigned short* dstp = (blk & 1) ? Qb : Kb;
          dstp[((size_t)(b * 2 + aa) * NN + n) * DD + d] = f2bf(val);
        } else {
          int aa = o >> 6, d = o & 63;
          Vt[((size_t)(b * 2 + aa) * DD + d) * NN + n] = f2bf(val);
        }
      }
}

// ---------------------------------------------------------------------------
// Kernel 4: flash attention. One block per (b, a, 64-row q-tile); 4 waves x 16
// q-rows. K/V staged in double-buffered XOR-swizzled LDS; P via per-wave LDS.
// ---------------------------------------------------------------------------
__global__ __launch_bounds__(256) void attn_kernel(
    const unsigned short* __restrict__ Qb, const unsigned short* __restrict__ Kb,
    const unsigned short* __restrict__ Vt, unsigned short* __restrict__ Ob)
{
  int qt = blockIdx.x;
  int a = blockIdx.y;
  int b = blockIdx.z;
  int ba = b * 2 + a;
  int tid = threadIdx.x;
  int w = tid >> 6;
  int lane = tid & 63;
  int lhi = lane >> 4, llo = lane & 15;

  __shared__ unsigned char ldsK[2][8192];
  __shared__ unsigned char ldsV[2][8192];
  __shared__ unsigned char ldsP[4][2048];

  const unsigned short* Qg = Qb + ((size_t)ba * NN + qt * 64 + w * 16) * DD;
  bf16x8 qf[2];
  qf[0] = *(const bf16x8*)(Qg + (size_t)llo * DD + lhi * 8);
  qf[1] = *(const bf16x8*)(Qg + (size_t)llo * DD + 32 + lhi * 8);

  const unsigned short* Kg = Kb + (size_t)ba * NN * DD;
  const unsigned short* Vg = Vt + (size_t)ba * DD * NN;

  f32x4 oacc[4] = {};
  float m[4], lsp[4];
#pragma unroll
  for (int r = 0; r < 4; ++r) { m[r] = -1e30f; lsp[r] = 0.f; }

  int sr = tid >> 3;           // staging row 0..31
  int sw = (tid & 7) * 16;     // byte offset within 128B row

  f32x4 kreg[2], vreg[2];
  // prologue: stage tile 0
#pragma unroll
  for (int i = 0; i < 2; ++i) {
    int r = i * 32 + sr;
    kreg[i] = *(const f32x4*)(Kg + (size_t)r * DD + (sw >> 1));
    vreg[i] = *(const f32x4*)(Vg + (size_t)r * NN + (sw >> 1));
  }
#pragma unroll
  for (int i = 0; i < 2; ++i) {
    int r = i * 32 + sr;
    int swz = sw ^ ((r & 7) << 4);
    *(f32x4*)(ldsK[0] + r * 128 + swz) = kreg[i];
    *(f32x4*)(ldsV[0] + r * 128 + swz) = vreg[i];
  }
  __syncthreads();

  int cur = 0;
  for (int it = 0; it < NN / 64; ++it) {
    // issue next tile's global loads early (latency hides under compute)
    if (it < NN / 64 - 1) {
      int kb = (it + 1) * 64;
#pragma unroll
      for (int i = 0; i < 2; ++i) {
        int r = i * 32 + sr;
        kreg[i] = *(const f32x4*)(Kg + (size_t)(kb + r) * DD + (sw >> 1));
        vreg[i] = *(const f32x4*)(Vg + (size_t)r * NN + kb + (sw >> 1));
      }
    }

    // S = Q @ K^T  (4 tiles of 16 k-rows)
    f32x4 s[4] = {};
#pragma unroll
    for (int t = 0; t < 4; ++t) {
      int krow = t * 16 + llo;
      int ksz = (krow & 7) << 4;
#pragma unroll
      for (int h = 0; h < 2; ++h) {
        bf16x8 kf = *(const bf16x8*)(ldsK[cur] + krow * 128 + ((h * 64 + lhi * 16) ^ ksz));
        s[t] = MFMA16(qf[h], kf, s[t]);
      }
    }

    // online softmax
#pragma unroll
    for (int r = 0; r < 4; ++r) {
      float pm = fmaxf(fmaxf(s[0][r], s[1][r]), fmaxf(s[2][r], s[3][r]));
      pm = fmaxf(pm, __shfl_xor(pm, 1));
      pm = fmaxf(pm, __shfl_xor(pm, 2));
      pm = fmaxf(pm, __shfl_xor(pm, 4));
      pm = fmaxf(pm, __shfl_xor(pm, 8));
      float mn = fmaxf(m[r], pm);
      float al = __expf(m[r] - mn);
      m[r] = mn;
      float ps = 0.f;
#pragma unroll
      for (int t = 0; t < 4; ++t) {
        float p = __expf(s[t][r] - mn);
        s[t][r] = p;
        ps += p;
      }
      lsp[r] = lsp[r] * al + ps;
#pragma unroll
      for (int dt = 0; dt < 4; ++dt) oacc[dt][r] *= al;
    }

    // P -> per-wave LDS (bf16, swizzled rows)
    unsigned char* Pw = ldsP[w];
#pragma unroll
    for (int r = 0; r < 4; ++r) {
      int q = lhi * 4 + r;
      int sz = (q & 7) << 4;
#pragma unroll
      for (int t = 0; t < 4; ++t) {
        int k2 = (t * 16 + llo) * 2;
        *(unsigned short*)(Pw + q * 128 + (k2 ^ sz)) = f2bf(s[t][r]);
      }
    }

    // O += P @ V
    bf16x8 pa[2];
#pragma unroll
    for (int kc = 0; kc < 2; ++kc)
      pa[kc] = *(const bf16x8*)(Pw + llo * 128 + ((kc * 64 + lhi * 16) ^ ((llo & 7) << 4)));
#pragma unroll
    for (int dt = 0; dt < 4; ++dt) {
      int vrow = dt * 16 + llo;
      int vsz = (vrow & 7) << 4;
#pragma unroll
      for (int kc = 0; kc < 2; ++kc) {
        bf16x8 vf = *(const bf16x8*)(ldsV[cur] + vrow * 128 + ((kc * 64 + lhi * 16) ^ vsz));
        oacc[dt] = MFMA16(pa[kc], vf, oacc[dt]);
      }
    }

    __syncthreads();
    if (it < NN / 64 - 1) {
#pragma unroll
      for (int i = 0; i < 2; ++i) {
        int r = i * 32 + sr;
        int swz = sw ^ ((r & 7) << 4);
        *(f32x4*)(ldsK[cur ^ 1] + r * 128 + swz) = kreg[i];
        *(f32x4*)(ldsV[cur ^ 1] + r * 128 + swz) = vreg[i];
      }
    }
    __syncthreads();
    cur ^= 1;
  }

  // epilogue: normalize + store O (b, n, 128) bf16
#pragma unroll
  for (int r = 0; r < 4; ++r) {
    float ls = lsp[r];
    ls += __shfl_xor(ls, 1);
    ls += __shfl_xor(ls, 2);
    ls += __shfl_xor(ls, 4);
    ls += __shfl_xor(ls, 8);
    float inv = 1.0f / ls;
    int q = qt * 64 + w * 16 + lhi * 4 + r;
    unsigned short* dst = Ob + ((size_t)b * NN + q) * 128 + a * 64 + llo;
#pragma unroll
    for (int dt = 0; dt < 4; ++dt) dst[dt * 16] = f2bf(oacc[dt][r] * inv);
  }
}

// ---------------------------------------------------------------------------
// Kernel 5: OUT[b,c,n] = sum_d WO[c,d]*O[b,n,d] + BO[c] + x[b,c,n]
// ---------------------------------------------------------------------------
__global__ __launch_bounds__(256) void out_kernel(
    const unsigned short* __restrict__ Ob, const unsigned short* __restrict__ WO,
    const float* __restrict__ BO, const float* __restrict__ x,
    float* __restrict__ out)
{
  int nt = blockIdx.x;  // 64-wide n tile
  int ct = blockIdx.y;  // 64-wide c tile
  int b = blockIdx.z;
  int w = threadIdx.x >> 6, lane = threadIdx.x & 63;
  int lhi = lane >> 4, llo = lane & 15;
  int cb = ct * 64 + w * 16;

  f32x4 acc[4] = {};
#pragma unroll
  for (int kc = 0; kc < 4; ++kc) {
    bf16x8 af = *(const bf16x8*)(WO + (size_t)(cb + llo) * 128 + kc * 32 + lhi * 8);
#pragma unroll
    for (int nn = 0; nn < 4; ++nn) {
      bf16x8 bfr = *(const bf16x8*)(Ob + ((size_t)b * NN + nt * 64 + nn * 16 + llo) * 128 + kc * 32 + lhi * 8);
      acc[nn] = MFMA16(af, bfr, acc[nn]);
    }
  }
#pragma unroll
  for (int nn = 0; nn < 4; ++nn)
#pragma unroll
    for (int r = 0; r < 4; ++r) {
      int c = cb + lhi * 4 + r;
      int n = nt * 64 + nn * 16 + llo;
      size_t idx = ((size_t)b * CC + c) * NN + n;
      out[idx] = acc[nn][r] + BO[c] + x[idx];
    }
}

// ---------------------------------------------------------------------------
extern "C" void kernel_launch(void* const* d_in, const int* in_sizes, int n_in,
                              void* d_out, int out_size, void* d_ws, size_t ws_size,
                              hipStream_t stream) {
  const float* x = (const float*)d_in[0];
  const float* x1 = (const float*)d_in[1];
  const float* x2 = (const float*)d_in[2];
  const float* bn1_g = (const float*)d_in[3];
  const float* bn1_b = (const float*)d_in[4];
  const float* bn1_m = (const float*)d_in[5];
  const float* bn1_v = (const float*)d_in[6];
  const float* bn2_g = (const float*)d_in[7];
  const float* bn2_b = (const float*)d_in[8];
  const float* bn2_m = (const float*)d_in[9];
  const float* bn2_v = (const float*)d_in[10];
  const float* kq1_w = (const float*)d_in[11];
  const float* kq1_b = (const float*)d_in[12];
  const float* kq2_w = (const float*)d_in[13];
  const float* kq2_b = (const float*)d_in[14];
  const float* v_w = (const float*)d_in[15];
  const float* v_b = (const float*)d_in[16];
  const float* out_w = (const float*)d_in[17];
  const float* out_b = (const float*)d_in[18];
  const float* bnl_g = (const float*)d_in[19];
  const float* bnl_b = (const float*)d_in[20];
  const float* bnl_m = (const float*)d_in[21];
  const float* bnl_v = (const float*)d_in[22];
  const float* w_scale = (const float*)d_in[23];

  char* ws = (char*)d_ws;
  const size_t XT_SZ = (size_t)NB * NN * CC * 2;        // 8 MB each
  const size_t QKV_SZ = (size_t)NB * 2 * NN * DD * 2;   // 4 MB each
  size_t off = 0;
  unsigned short* XT0 = (unsigned short*)(ws + off); off += XT_SZ;
  unsigned short* XT1 = (unsigned short*)(ws + off); off += XT_SZ;
  unsigned short* XT2 = (unsigned short*)(ws + off); off += XT_SZ;
  unsigned short* Qb = (unsigned short*)(ws + off); off += QKV_SZ;
  unsigned short* Kb = (unsigned short*)(ws + off); off += QKV_SZ;
  unsigned short* Vt = (unsigned short*)(ws + off); off += QKV_SZ;
  unsigned short* Ob = (unsigned short*)(ws + off); off += (size_t)NB * NN * 128 * 2;
  unsigned short* W1 = (unsigned short*)(ws + off); off += 128 * CC * 2;
  unsigned short* W2 = (unsigned short*)(ws + off); off += 128 * CC * 2;
  unsigned short* WV = (unsigned short*)(ws + off); off += 128 * CC * 2;
  unsigned short* WO = (unsigned short*)(ws + off); off += CC * 128 * 2;
  float* B1 = (float*)(ws + off); off += 512;
  float* B2 = (float*)(ws + off); off += 512;
  float* BV = (float*)(ws + off); off += 512;
  float* BO = (float*)(ws + off); off += 1024;
  if (ws_size < off) return;  // loud failure: output stays poisoned

  prep_kernel<<<4, 256, 0, stream>>>(
      kq1_w, kq1_b, kq2_w, kq2_b, v_w, v_b, out_w, out_b,
      bn1_g, bn1_b, bn1_m, bn1_v, bn2_g, bn2_b, bn2_m, bn2_v,
      bnl_g, bnl_b, bnl_m, bnl_v, w_scale,
      W1, W2, WV, WO, B1, B2, BV, BO);

  conv_kernel<<<dim3(64, 4, 12), 256, 0, stream>>>(x, x1, x2, XT0, XT1, XT2);

  proj_kernel<<<dim3(64, 3, 4), 256, 0, stream>>>(
      XT0, XT1, XT2, W1, W2, WV, B1, B2, BV, Qb, Kb, Vt);

  attn_kernel<<<dim3(64, 2, 4), 256, 0, stream>>>(Qb, Kb, Vt, Ob);

  out_kernel<<<dim3(64, 4, 4), 256, 0, stream>>>(Ob, WO, BO, x, (float*)d_out);
}

// Round 3
// 180.592 us; speedup vs baseline: 1.0824x; 1.0824x over previous
//
#include <hip/hip_runtime.h>

typedef short bf16x8 __attribute__((ext_vector_type(8)));
typedef float f32x4 __attribute__((ext_vector_type(4)));

#define MFMA16(A, B, C) __builtin_amdgcn_mfma_f32_16x16x32_bf16((A), (B), (C), 0, 0, 0)

static constexpr int NB = 4;       // batch
static constexpr int CC = 256;     // channels (INC1 == INC2)
static constexpr int NN = 4096;    // H*W
static constexpr int DD = 64;      // head dim

__device__ __forceinline__ unsigned short f2bf(float f) {
  unsigned int u = __builtin_bit_cast(unsigned int, f);
  u += 0x7fffu + ((u >> 16) & 1u);
  return (unsigned short)(u >> 16);
}

// ---------------------------------------------------------------------------
// Kernel 1: fold BN into projection weights, bf16-cast weights, build biases.
// ---------------------------------------------------------------------------
__global__ void prep_kernel(
    const float* __restrict__ kq1_w, const float* __restrict__ kq1_b,
    const float* __restrict__ kq2_w, const float* __restrict__ kq2_b,
    const float* __restrict__ v_w,   const float* __restrict__ v_b,
    const float* __restrict__ out_w, const float* __restrict__ out_b,
    const float* __restrict__ bn1_g, const float* __restrict__ bn1_b,
    const float* __restrict__ bn1_m, const float* __restrict__ bn1_v,
    const float* __restrict__ bn2_g, const float* __restrict__ bn2_b,
    const float* __restrict__ bn2_m, const float* __restrict__ bn2_v,
    const float* __restrict__ bnl_g, const float* __restrict__ bnl_b,
    const float* __restrict__ bnl_m, const float* __restrict__ bnl_v,
    const float* __restrict__ w_scale,
    unsigned short* __restrict__ W1, unsigned short* __restrict__ W2,
    unsigned short* __restrict__ WV, unsigned short* __restrict__ WO,
    float* __restrict__ B1, float* __restrict__ B2,
    float* __restrict__ BV, float* __restrict__ BO)
{
  int blk = blockIdx.x;
  int t = threadIdx.x;
  if (blk == 0) {
    if (t < 128) {
      float acc = kq1_b[t];
      for (int c = 0; c < CC; ++c) {
        float s = bn1_g[c] * rsqrtf(bn1_v[c] + 1e-5f);
        float off = bn1_b[c] - bn1_m[c] * s;
        W1[t * CC + c] = f2bf(kq1_w[t * CC + c] * s);
        acc += kq1_w[t * CC + c] * off;
      }
      B1[t] = acc;
    }
  } else if (blk == 1) {
    if (t < 128) {
      float acc = kq2_b[t];
      for (int c = 0; c < CC; ++c) {
        float s = bn2_g[c] * rsqrtf(bn2_v[c] + 1e-5f);
        float off = bn2_b[c] - bn2_m[c] * s;
        W2[t * CC + c] = f2bf(kq2_w[t * CC + c] * s);
        acc += kq2_w[t * CC + c] * off;
      }
      B2[t] = acc;
    }
  } else if (blk == 2) {
    if (t < 128) {
      for (int c = 0; c < CC; ++c) WV[t * CC + c] = f2bf(v_w[t * CC + c]);
      BV[t] = v_b[t];
    }
  } else {
    float s = bnl_g[t] * rsqrtf(bnl_v[t] + 1e-5f);
    float ws = w_scale[0];
    for (int d = 0; d < 128; ++d) WO[t * 128 + d] = f2bf(ws * s * out_w[t * 128 + d]);
    BO[t] = ws * (out_b[t] * s + bnl_b[t] - bnl_m[t] * s);
  }
}

// ---------------------------------------------------------------------------
// Kernel 2: NCHW f32 -> (b, n, c) bf16 transpose-cast via LDS 64x64 tiles.
// ---------------------------------------------------------------------------
__global__ __launch_bounds__(256) void conv_kernel(
    const float* __restrict__ x, const float* __restrict__ x1, const float* __restrict__ x2,
    unsigned short* __restrict__ t0, unsigned short* __restrict__ t1, unsigned short* __restrict__ t2)
{
  int tensor = blockIdx.z >> 2, b = blockIdx.z & 3;
  const float* src = tensor == 0 ? x : (tensor == 1 ? x1 : x2);
  unsigned short* dst = tensor == 0 ? t0 : (tensor == 1 ? t1 : t2);
  int cb = blockIdx.y * 64, nb = blockIdx.x * 64;
  __shared__ float tile[64][65];
  int t = threadIdx.x;
  int cl = t >> 2, n0 = (t & 3) * 16;
  const float* s = src + ((size_t)b * CC + cb + cl) * NN + nb + n0;
  f32x4 v0 = *(const f32x4*)(s);
  f32x4 v1 = *(const f32x4*)(s + 4);
  f32x4 v2 = *(const f32x4*)(s + 8);
  f32x4 v3 = *(const f32x4*)(s + 12);
#pragma unroll
  for (int j = 0; j < 4; ++j) {
    tile[cl][n0 + j] = v0[j];
    tile[cl][n0 + 4 + j] = v1[j];
    tile[cl][n0 + 8 + j] = v2[j];
    tile[cl][n0 + 12 + j] = v3[j];
  }
  __syncthreads();
  int nl = t >> 2, c0 = (t & 3) * 16;
  unsigned short* d = dst + ((size_t)b * NN + nb + nl) * CC + cb + c0;
  alignas(16) unsigned short tmp[16];
#pragma unroll
  for (int j = 0; j < 16; ++j) tmp[j] = f2bf(tile[c0 + j][nl]);
  *(bf16x8*)(d) = *(const bf16x8*)(tmp);
  *(bf16x8*)(d + 8) = *(const bf16x8*)(tmp + 8);
}

// ---------------------------------------------------------------------------
// Kernel 3: projections. Q pre-scaled by 1/sqrt(64)=0.125 (natural-exp domain).
// ---------------------------------------------------------------------------
__global__ __launch_bounds__(256) void proj_kernel(
    const unsigned short* __restrict__ Xt0, const unsigned short* __restrict__ Xt1,
    const unsigned short* __restrict__ Xt2,
    const unsigned short* __restrict__ W1, const unsigned short* __restrict__ W2,
    const unsigned short* __restrict__ WV,
    const float* __restrict__ B1, const float* __restrict__ B2, const float* __restrict__ BV,
    unsigned short* __restrict__ Qb, unsigned short* __restrict__ Kb,
    unsigned short* __restrict__ Vt)
{
  int nt = blockIdx.x;
  int mat = blockIdx.y;
  int b = blockIdx.z;
  const unsigned short* X =
      (mat == 0 ? Xt1 : (mat == 1 ? Xt2 : Xt0)) + (size_t)b * NN * CC;
  const unsigned short* W = mat == 0 ? W1 : (mat == 1 ? W2 : WV);
  const float* Bi = mat == 0 ? B1 : (mat == 1 ? B2 : BV);
  int w = threadIdx.x >> 6, lane = threadIdx.x & 63;
  int lhi = lane >> 4, llo = lane & 15;
  int ob = w * 32;

  f32x4 acc[2][4] = {};
#pragma unroll
  for (int kc = 0; kc < 8; ++kc) {
    bf16x8 af[2], bfr[4];
#pragma unroll
    for (int ot = 0; ot < 2; ++ot)
      af[ot] = *(const bf16x8*)(W + (size_t)(ob + ot * 16 + llo) * CC + kc * 32 + lhi * 8);
#pragma unroll
    for (int nn = 0; nn < 4; ++nn)
      bfr[nn] = *(const bf16x8*)(X + ((size_t)nt * 64 + nn * 16 + llo) * CC + kc * 32 + lhi * 8);
#pragma unroll
    for (int ot = 0; ot < 2; ++ot)
#pragma unroll
      for (int nn = 0; nn < 4; ++nn)
        acc[ot][nn] = MFMA16(af[ot], bfr[nn], acc[ot][nn]);
  }

#pragma unroll
  for (int ot = 0; ot < 2; ++ot)
#pragma unroll
    for (int nn = 0; nn < 4; ++nn)
#pragma unroll
      for (int r = 0; r < 4; ++r) {
        int o = ob + ot * 16 + lhi * 4 + r;
        int n = nt * 64 + nn * 16 + llo;
        float val = acc[ot][nn][r] + Bi[o];
        if (mat < 2) {
          int blk = o >> 5;              // 0:K a0  1:Q a0  2:K a1  3:Q a1
          int aa = blk >> 1;
          int d = (o & 31) + mat * 32;
          if (blk & 1) val *= 0.125f;
          unsigned short* dstp = (blk & 1) ? Qb : Kb;
          dstp[((size_t)(b * 2 + aa) * NN + n) * DD + d] = f2bf(val);
        } else {
          int aa = o >> 6, d = o & 63;
          Vt[((size_t)(b * 2 + aa) * DD + d) * NN + n] = f2bf(val);
        }
      }
}

// ---------------------------------------------------------------------------
// Kernel 4: flash attention. R1-verified internals + in-block K-split.
// Block = 32 q-rows; wave w: wq=w&1 -> 16-q subtile, wk=w>>1 -> k-half (2048).
// Single-buffered K/V LDS stream per k-half; per-wave LDS P transpose.
// ---------------------------------------------------------------------------
__global__ __launch_bounds__(256, 4) void attn_kernel(
    const unsigned short* __restrict__ Qb, const unsigned short* __restrict__ Kb,
    const unsigned short* __restrict__ Vt, unsigned short* __restrict__ Ob)
{
  int qt = blockIdx.x;
  int a = blockIdx.y;
  int b = blockIdx.z;
  int ba = b * 2 + a;
  int tid = threadIdx.x;
  int w = tid >> 6;
  int lane = tid & 63;
  int lhi = lane >> 4, llo = lane & 15;
  int wq = w & 1, wk = w >> 1;

  __shared__ char ldsKV[32768];          // [wk][ K 8KB | V 8KB ]
  __shared__ char ldsP[4][2048];
  char* Ks = ldsKV + wk * 16384;
  char* Vs = Ks + 8192;

  // Q fragments: lane (llo,lhi) holds Q[q=llo][d = h*32 + lhi*8 ..+8]
  const unsigned short* Qg = Qb + ((size_t)ba * NN + qt * 32 + wq * 16) * DD;
  bf16x8 qf[2];
  qf[0] = *(const bf16x8*)(Qg + (size_t)llo * DD + lhi * 8);
  qf[1] = *(const bf16x8*)(Qg + (size_t)llo * DD + 32 + lhi * 8);

  const unsigned short* Kg = Kb + ((size_t)ba * NN + wk * 2048) * DD;
  const unsigned short* Vg = Vt + (size_t)ba * DD * NN + wk * 2048;

  f32x4 oacc[4] = {};
  float m[4], lsp[4];
#pragma unroll
  for (int r = 0; r < 4; ++r) { m[r] = -1e30f; lsp[r] = 0.f; }

  // staging: 128 threads per k-half stream; (row, 16B-slot) per thread x4
  int t7 = tid & 127;
  int sr8 = t7 >> 3, scol = t7 & 7;

  f32x4 kreg[4], vreg[4];
#define STAGE_LOAD(IT)                                                        \
  {                                                                           \
    int kb_ = (IT) * 64;                                                      \
    _Pragma("unroll") for (int i = 0; i < 4; ++i) {                           \
      int row = i * 16 + sr8;                                                 \
      kreg[i] = *(const f32x4*)(Kg + (size_t)(kb_ + row) * DD + scol * 8);    \
      vreg[i] = *(const f32x4*)(Vg + (size_t)row * NN + kb_ + scol * 8);      \
    }                                                                         \
  }
#define STAGE_WRITE()                                                         \
  {                                                                           \
    _Pragma("unroll") for (int i = 0; i < 4; ++i) {                           \
      int row = i * 16 + sr8;                                                 \
      int swz = (scol * 16) ^ ((row & 7) << 4);                               \
      *(f32x4*)(Ks + row * 128 + swz) = kreg[i];                              \
      *(f32x4*)(Vs + row * 128 + swz) = vreg[i];                              \
    }                                                                         \
  }

  STAGE_LOAD(0);
  STAGE_WRITE();
  __syncthreads();

  for (int it = 0; it < 32; ++it) {
    if (it < 31) STAGE_LOAD(it + 1);

    // S = Q @ K^T : s[t][r] = S[q = lhi*4+r][k = t*16+llo]
    f32x4 s[4] = {};
#pragma unroll
    for (int t = 0; t < 4; ++t) {
      int krow = t * 16 + llo;
      int ksz = (krow & 7) << 4;
#pragma unroll
      for (int h = 0; h < 2; ++h) {
        bf16x8 kf = *(const bf16x8*)(Ks + krow * 128 + ((h * 64 + lhi * 16) ^ ksz));
        s[t] = MFMA16(qf[h], kf, s[t]);
      }
    }

    // online softmax (R1-verified form)
#pragma unroll
    for (int r = 0; r < 4; ++r) {
      float pm = fmaxf(fmaxf(s[0][r], s[1][r]), fmaxf(s[2][r], s[3][r]));
      pm = fmaxf(pm, __shfl_xor(pm, 1));
      pm = fmaxf(pm, __shfl_xor(pm, 2));
      pm = fmaxf(pm, __shfl_xor(pm, 4));
      pm = fmaxf(pm, __shfl_xor(pm, 8));
      float mn = fmaxf(m[r], pm);
      float al = __expf(m[r] - mn);
      m[r] = mn;
      float ps = 0.f;
#pragma unroll
      for (int t = 0; t < 4; ++t) {
        float p = __expf(s[t][r] - mn);
        s[t][r] = p;
        ps += p;
      }
      lsp[r] = lsp[r] * al + ps;
#pragma unroll
      for (int dt = 0; dt < 4; ++dt) oacc[dt][r] *= al;
    }

    // P -> per-wave LDS (bf16, swizzled rows)
    char* Pw = ldsP[w];
#pragma unroll
    for (int r = 0; r < 4; ++r) {
      int q = lhi * 4 + r;
      int sz = (q & 7) << 4;
#pragma unroll
      for (int t = 0; t < 4; ++t) {
        int k2 = (t * 16 + llo) * 2;
        *(unsigned short*)(Pw + q * 128 + (k2 ^ sz)) = f2bf(s[t][r]);
      }
    }

    // O += P @ V
    bf16x8 pa[2];
#pragma unroll
    for (int kc = 0; kc < 2; ++kc)
      pa[kc] = *(const bf16x8*)(Pw + llo * 128 + ((kc * 64 + lhi * 16) ^ ((llo & 7) << 4)));
#pragma unroll
    for (int dt = 0; dt < 4; ++dt) {
      int vrow = dt * 16 + llo;
      int vsz = (vrow & 7) << 4;
#pragma unroll
      for (int kc = 0; kc < 2; ++kc) {
        bf16x8 vf = *(const bf16x8*)(Vs + vrow * 128 + ((kc * 64 + lhi * 16) ^ vsz));
        oacc[dt] = MFMA16(pa[kc], vf, oacc[dt]);
      }
    }

    __syncthreads();
    if (it < 31) STAGE_WRITE();
    __syncthreads();
  }

  // reduce partial row-sums across the 16 llo lanes
#pragma unroll
  for (int r = 0; r < 4; ++r) {
    float ls = lsp[r];
    ls += __shfl_xor(ls, 1);
    ls += __shfl_xor(ls, 2);
    ls += __shfl_xor(ls, 4);
    ls += __shfl_xor(ls, 8);
    lsp[r] = ls;
  }

  // merge the two k-halves via LDS (reuse wk0's K/V region; barrier-separated)
  float* mO = (float*)ldsKV;             // [2][16][64] f32 partial O (wk=1)
  float* mM = (float*)(ldsKV + 8192);    // [2][16] running max
  float* mL = (float*)(ldsKV + 8192 + 128);
  if (wk == 1) {
#pragma unroll
    for (int r = 0; r < 4; ++r) {
      int ql = lhi * 4 + r;
#pragma unroll
      for (int dt = 0; dt < 4; ++dt)
        mO[(wq * 16 + ql) * 64 + dt * 16 + llo] = oacc[dt][r];
      if (llo == 0) { mM[wq * 16 + ql] = m[r]; mL[wq * 16 + ql] = lsp[r]; }
    }
  }
  __syncthreads();
  if (wk == 0) {
#pragma unroll
    for (int r = 0; r < 4; ++r) {
      int ql = lhi * 4 + r;
      float m2 = mM[wq * 16 + ql], l2 = mL[wq * 16 + ql];
      float mf = fmaxf(m[r], m2);
      float e1 = __expf(m[r] - mf);
      float e2 = __expf(m2 - mf);
      float inv = 1.f / (lsp[r] * e1 + l2 * e2);
      int q = qt * 32 + wq * 16 + ql;
      unsigned short* dst = Ob + ((size_t)b * NN + q) * 128 + a * 64 + llo;
#pragma unroll
      for (int dt = 0; dt < 4; ++dt)
        dst[dt * 16] =
            f2bf((oacc[dt][r] * e1 + mO[(wq * 16 + ql) * 64 + dt * 16 + llo] * e2) * inv);
    }
  }
}

// ---------------------------------------------------------------------------
// Kernel 5: OUT[b,c,n] = sum_d WO[c,d]*O[b,n,d] + BO[c] + x[b,c,n]
// ---------------------------------------------------------------------------
__global__ __launch_bounds__(256) void out_kernel(
    const unsigned short* __restrict__ Ob, const unsigned short* __restrict__ WO,
    const float* __restrict__ BO, const float* __restrict__ x,
    float* __restrict__ out)
{
  int nt = blockIdx.x;
  int ct = blockIdx.y;
  int b = blockIdx.z;
  int w = threadIdx.x >> 6, lane = threadIdx.x & 63;
  int lhi = lane >> 4, llo = lane & 15;
  int cb = ct * 64 + w * 16;

  f32x4 acc[4] = {};
#pragma unroll
  for (int kc = 0; kc < 4; ++kc) {
    bf16x8 af = *(const bf16x8*)(WO + (size_t)(cb + llo) * 128 + kc * 32 + lhi * 8);
#pragma unroll
    for (int nn = 0; nn < 4; ++nn) {
      bf16x8 bfr = *(const bf16x8*)(Ob + ((size_t)b * NN + nt * 64 + nn * 16 + llo) * 128 + kc * 32 + lhi * 8);
      acc[nn] = MFMA16(af, bfr, acc[nn]);
    }
  }
#pragma unroll
  for (int nn = 0; nn < 4; ++nn)
#pragma unroll
    for (int r = 0; r < 4; ++r) {
      int c = cb + lhi * 4 + r;
      int n = nt * 64 + nn * 16 + llo;
      size_t idx = ((size_t)b * CC + c) * NN + n;
      out[idx] = acc[nn][r] + BO[c] + x[idx];
    }
}

// ---------------------------------------------------------------------------
extern "C" void kernel_launch(void* const* d_in, const int* in_sizes, int n_in,
                              void* d_out, int out_size, void* d_ws, size_t ws_size,
                              hipStream_t stream) {
  const float* x = (const float*)d_in[0];
  const float* x1 = (const float*)d_in[1];
  const float* x2 = (const float*)d_in[2];
  const float* bn1_g = (const float*)d_in[3];
  const float* bn1_b = (const float*)d_in[4];
  const float* bn1_m = (const float*)d_in[5];
  const float* bn1_v = (const float*)d_in[6];
  const float* bn2_g = (const float*)d_in[7];
  const float* bn2_b = (const float*)d_in[8];
  const float* bn2_m = (const float*)d_in[9];
  const float* bn2_v = (const float*)d_in[10];
  const float* kq1_w = (const float*)d_in[11];
  const float* kq1_b = (const float*)d_in[12];
  const float* kq2_w = (const float*)d_in[13];
  const float* kq2_b = (const float*)d_in[14];
  const float* v_w = (const float*)d_in[15];
  const float* v_b = (const float*)d_in[16];
  const float* out_w = (const float*)d_in[17];
  const float* out_b = (const float*)d_in[18];
  const float* bnl_g = (const float*)d_in[19];
  const float* bnl_b = (const float*)d_in[20];
  const float* bnl_m = (const float*)d_in[21];
  const float* bnl_v = (const float*)d_in[22];
  const float* w_scale = (const float*)d_in[23];

  char* ws = (char*)d_ws;
  const size_t XT_SZ = (size_t)NB * NN * CC * 2;        // 8 MB each
  const size_t QKV_SZ = (size_t)NB * 2 * NN * DD * 2;   // 4 MB each
  size_t off = 0;
  unsigned short* XT0 = (unsigned short*)(ws + off); off += XT_SZ;
  unsigned short* XT1 = (unsigned short*)(ws + off); off += XT_SZ;
  unsigned short* XT2 = (unsigned short*)(ws + off); off += XT_SZ;
  unsigned short* Qb = (unsigned short*)(ws + off); off += QKV_SZ;
  unsigned short* Kb = (unsigned short*)(ws + off); off += QKV_SZ;
  unsigned short* Vt = (unsigned short*)(ws + off); off += QKV_SZ;
  unsigned short* Ob = (unsigned short*)(ws + off); off += (size_t)NB * NN * 128 * 2;
  unsigned short* W1 = (unsigned short*)(ws + off); off += 128 * CC * 2;
  unsigned short* W2 = (unsigned short*)(ws + off); off += 128 * CC * 2;
  unsigned short* WV = (unsigned short*)(ws + off); off += 128 * CC * 2;
  unsigned short* WO = (unsigned short*)(ws + off); off += CC * 128 * 2;
  float* B1 = (float*)(ws + off); off += 512;
  float* B2 = (float*)(ws + off); off += 512;
  float* BV = (float*)(ws + off); off += 512;
  float* BO = (float*)(ws + off); off += 1024;
  if (ws_size < off) return;  // loud failure: output stays poisoned

  prep_kernel<<<4, 256, 0, stream>>>(
      kq1_w, kq1_b, kq2_w, kq2_b, v_w, v_b, out_w, out_b,
      bn1_g, bn1_b, bn1_m, bn1_v, bn2_g, bn2_b, bn2_m, bn2_v,
      bnl_g, bnl_b, bnl_m, bnl_v, w_scale,
      W1, W2, WV, WO, B1, B2, BV, BO);

  conv_kernel<<<dim3(64, 4, 12), 256, 0, stream>>>(x, x1, x2, XT0, XT1, XT2);

  proj_kernel<<<dim3(64, 3, 4), 256, 0, stream>>>(
      XT0, XT1, XT2, W1, W2, WV, B1, B2, BV, Qb, Kb, Vt);

  attn_kernel<<<dim3(128, 2, 4), 256, 0, stream>>>(Qb, Kb, Vt, Ob);

  out_kernel<<<dim3(64, 4, 4), 256, 0, stream>>>(Ob, WO, BO, x, (float*)d_out);
}

// Round 4
// 154.520 us; speedup vs baseline: 1.2651x; 1.1687x over previous
//
#include <hip/hip_runtime.h>

typedef short bf16x8 __attribute__((ext_vector_type(8)));
typedef float f32x4 __attribute__((ext_vector_type(4)));

#define MFMA16(A, B, C) __builtin_amdgcn_mfma_f32_16x16x32_bf16((A), (B), (C), 0, 0, 0)

static constexpr int NB = 4;       // batch
static constexpr int CC = 256;     // channels (INC1 == INC2)
static constexpr int NN = 4096;    // H*W
static constexpr int DD = 64;      // head dim

__device__ __forceinline__ unsigned short f2bf(float f) {
  unsigned int u = __builtin_bit_cast(unsigned int, f);
  u += 0x7fffu + ((u >> 16) & 1u);
  return (unsigned short)(u >> 16);
}

__device__ __forceinline__ unsigned int pk2(float lo, float hi) {
  return (unsigned int)f2bf(lo) | ((unsigned int)f2bf(hi) << 16);
}

// ---------------------------------------------------------------------------
// Kernel 1: fold BN into projection weights, bf16-cast weights, build biases.
// ---------------------------------------------------------------------------
__global__ void prep_kernel(
    const float* __restrict__ kq1_w, const float* __restrict__ kq1_b,
    const float* __restrict__ kq2_w, const float* __restrict__ kq2_b,
    const float* __restrict__ v_w,   const float* __restrict__ v_b,
    const float* __restrict__ out_w, const float* __restrict__ out_b,
    const float* __restrict__ bn1_g, const float* __restrict__ bn1_b,
    const float* __restrict__ bn1_m, const float* __restrict__ bn1_v,
    const float* __restrict__ bn2_g, const float* __restrict__ bn2_b,
    const float* __restrict__ bn2_m, const float* __restrict__ bn2_v,
    const float* __restrict__ bnl_g, const float* __restrict__ bnl_b,
    const float* __restrict__ bnl_m, const float* __restrict__ bnl_v,
    const float* __restrict__ w_scale,
    unsigned short* __restrict__ W1, unsigned short* __restrict__ W2,
    unsigned short* __restrict__ WV, unsigned short* __restrict__ WO,
    float* __restrict__ B1, float* __restrict__ B2,
    float* __restrict__ BV, float* __restrict__ BO)
{
  int blk = blockIdx.x;
  int t = threadIdx.x;
  if (blk == 0) {
    if (t < 128) {
      float acc = kq1_b[t];
      for (int c = 0; c < CC; ++c) {
        float s = bn1_g[c] * rsqrtf(bn1_v[c] + 1e-5f);
        float off = bn1_b[c] - bn1_m[c] * s;
        W1[t * CC + c] = f2bf(kq1_w[t * CC + c] * s);
        acc += kq1_w[t * CC + c] * off;
      }
      B1[t] = acc;
    }
  } else if (blk == 1) {
    if (t < 128) {
      float acc = kq2_b[t];
      for (int c = 0; c < CC; ++c) {
        float s = bn2_g[c] * rsqrtf(bn2_v[c] + 1e-5f);
        float off = bn2_b[c] - bn2_m[c] * s;
        W2[t * CC + c] = f2bf(kq2_w[t * CC + c] * s);
        acc += kq2_w[t * CC + c] * off;
      }
      B2[t] = acc;
    }
  } else if (blk == 2) {
    if (t < 128) {
      for (int c = 0; c < CC; ++c) WV[t * CC + c] = f2bf(v_w[t * CC + c]);
      BV[t] = v_b[t];
    }
  } else {
    float s = bnl_g[t] * rsqrtf(bnl_v[t] + 1e-5f);
    float ws = w_scale[0];
    for (int d = 0; d < 128; ++d) WO[t * 128 + d] = f2bf(ws * s * out_w[t * 128 + d]);
    BO[t] = ws * (out_b[t] * s + bnl_b[t] - bnl_m[t] * s);
  }
}

// ---------------------------------------------------------------------------
// Kernel 2: NCHW f32 -> (b, n, c) bf16 transpose-cast via LDS 64x64 tiles.
// ---------------------------------------------------------------------------
__global__ __launch_bounds__(256) void conv_kernel(
    const float* __restrict__ x, const float* __restrict__ x1, const float* __restrict__ x2,
    unsigned short* __restrict__ t0, unsigned short* __restrict__ t1, unsigned short* __restrict__ t2)
{
  int tensor = blockIdx.z >> 2, b = blockIdx.z & 3;
  const float* src = tensor == 0 ? x : (tensor == 1 ? x1 : x2);
  unsigned short* dst = tensor == 0 ? t0 : (tensor == 1 ? t1 : t2);
  int cb = blockIdx.y * 64, nb = blockIdx.x * 64;
  __shared__ float tile[64][65];
  int t = threadIdx.x;
  int cl = t >> 2, n0 = (t & 3) * 16;
  const float* s = src + ((size_t)b * CC + cb + cl) * NN + nb + n0;
  f32x4 v0 = *(const f32x4*)(s);
  f32x4 v1 = *(const f32x4*)(s + 4);
  f32x4 v2 = *(const f32x4*)(s + 8);
  f32x4 v3 = *(const f32x4*)(s + 12);
#pragma unroll
  for (int j = 0; j < 4; ++j) {
    tile[cl][n0 + j] = v0[j];
    tile[cl][n0 + 4 + j] = v1[j];
    tile[cl][n0 + 8 + j] = v2[j];
    tile[cl][n0 + 12 + j] = v3[j];
  }
  __syncthreads();
  int nl = t >> 2, c0 = (t & 3) * 16;
  unsigned short* d = dst + ((size_t)b * NN + nb + nl) * CC + cb + c0;
  alignas(16) unsigned short tmp[16];
#pragma unroll
  for (int j = 0; j < 16; ++j) tmp[j] = f2bf(tile[c0 + j][nl]);
  *(bf16x8*)(d) = *(const bf16x8*)(tmp);
  *(bf16x8*)(d + 8) = *(const bf16x8*)(tmp + 8);
}

// ---------------------------------------------------------------------------
// Kernel 3: projections. Q pre-scaled by 1/sqrt(64)=0.125 (natural-exp domain).
// ---------------------------------------------------------------------------
__global__ __launch_bounds__(256) void proj_kernel(
    const unsigned short* __restrict__ Xt0, const unsigned short* __restrict__ Xt1,
    const unsigned short* __restrict__ Xt2,
    const unsigned short* __restrict__ W1, const unsigned short* __restrict__ W2,
    const unsigned short* __restrict__ WV,
    const float* __restrict__ B1, const float* __restrict__ B2, const float* __restrict__ BV,
    unsigned short* __restrict__ Qb, unsigned short* __restrict__ Kb,
    unsigned short* __restrict__ Vt)
{
  int nt = blockIdx.x;
  int mat = blockIdx.y;
  int b = blockIdx.z;
  const unsigned short* X =
      (mat == 0 ? Xt1 : (mat == 1 ? Xt2 : Xt0)) + (size_t)b * NN * CC;
  const unsigned short* W = mat == 0 ? W1 : (mat == 1 ? W2 : WV);
  const float* Bi = mat == 0 ? B1 : (mat == 1 ? B2 : BV);
  int w = threadIdx.x >> 6, lane = threadIdx.x & 63;
  int lhi = lane >> 4, llo = lane & 15;
  int ob = w * 32;

  f32x4 acc[2][4] = {};
#pragma unroll
  for (int kc = 0; kc < 8; ++kc) {
    bf16x8 af[2], bfr[4];
#pragma unroll
    for (int ot = 0; ot < 2; ++ot)
      af[ot] = *(const bf16x8*)(W + (size_t)(ob + ot * 16 + llo) * CC + kc * 32 + lhi * 8);
#pragma unroll
    for (int nn = 0; nn < 4; ++nn)
      bfr[nn] = *(const bf16x8*)(X + ((size_t)nt * 64 + nn * 16 + llo) * CC + kc * 32 + lhi * 8);
#pragma unroll
    for (int ot = 0; ot < 2; ++ot)
#pragma unroll
      for (int nn = 0; nn < 4; ++nn)
        acc[ot][nn] = MFMA16(af[ot], bfr[nn], acc[ot][nn]);
  }

#pragma unroll
  for (int ot = 0; ot < 2; ++ot)
#pragma unroll
    for (int nn = 0; nn < 4; ++nn)
#pragma unroll
      for (int r = 0; r < 4; ++r) {
        int o = ob + ot * 16 + lhi * 4 + r;
        int n = nt * 64 + nn * 16 + llo;
        float val = acc[ot][nn][r] + Bi[o];
        if (mat < 2) {
          int blk = o >> 5;              // 0:K a0  1:Q a0  2:K a1  3:Q a1
          int aa = blk >> 1;
          int d = (o & 31) + mat * 32;
          if (blk & 1) val *= 0.125f;
          unsigned short* dstp = (blk & 1) ? Qb : Kb;
          dstp[((size_t)(b * 2 + aa) * NN + n) * DD + d] = f2bf(val);
        } else {
          int aa = o >> 6, d = o & 63;
          Vt[((size_t)(b * 2 + aa) * DD + d) * NN + n] = f2bf(val);
        }
      }
}

// ---------------------------------------------------------------------------
// Kernel 4: flash attention, swapped-QK^T. R3 structure (k-split, staging,
// swizzles, merge) with S^T = mfma(K_perm, Q):
//   A-row llo at step t loads K-row krow = 32(t&1) + 8(llo>>2) + 4(t>>1) + (llo&3)
//   => s[t][r] (lane llo,lhi) = S[q=llo][k = 32(t&1) + 8lhi + 4(t>>1) + r]
//   => lane's 16 P values are exactly its PV B-fragment (k = h*32+lhi*8+j):
//      F0 slots j=0..7 <- s[0][0..3], s[2][0..3]; F1 <- s[1], s[3].
// Softmax per-lane (one q), 2 shfls for max; sum reduced after the loop.
// ---------------------------------------------------------------------------
__global__ __launch_bounds__(256, 4) void attn_kernel(
    const unsigned short* __restrict__ Qb, const unsigned short* __restrict__ Kb,
    const unsigned short* __restrict__ Vt, unsigned short* __restrict__ Ob)
{
  int qt = blockIdx.x;
  int a = blockIdx.y;
  int b = blockIdx.z;
  int ba = b * 2 + a;
  int tid = threadIdx.x;
  int w = tid >> 6;
  int lane = tid & 63;
  int lhi = lane >> 4, llo = lane & 15;
  int wq = w & 1, wk = w >> 1;

  __shared__ char ldsKV[32768];          // [wk][ K 8KB | V 8KB ]
  char* Ks = ldsKV + wk * 16384;
  char* Vs = Ks + 8192;

  // Q as B-operand: lane (llo,lhi) holds Q[q=llo][d = h*32 + lhi*8 ..+8]
  const unsigned short* Qg = Qb + ((size_t)ba * NN + qt * 32 + wq * 16) * DD;
  bf16x8 qf[2];
  qf[0] = *(const bf16x8*)(Qg + (size_t)llo * DD + lhi * 8);
  qf[1] = *(const bf16x8*)(Qg + (size_t)llo * DD + 32 + lhi * 8);

  const unsigned short* Kg = Kb + ((size_t)ba * NN + wk * 2048) * DD;
  const unsigned short* Vg = Vt + (size_t)ba * DD * NN + wk * 2048;

  f32x4 oacc[4] = {};
  float m = -1e30f, lsum = 0.f;

  // staging: 128 threads per k-half stream; (row, 16B-slot) per thread x4
  int t7 = tid & 127;
  int sr8 = t7 >> 3, scol = t7 & 7;

  f32x4 kreg[4], vreg[4];
#define STAGE_LOAD(IT)                                                        \
  {                                                                           \
    int kb_ = (IT) * 64;                                                      \
    _Pragma("unroll") for (int i = 0; i < 4; ++i) {                           \
      int row = i * 16 + sr8;                                                 \
      kreg[i] = *(const f32x4*)(Kg + (size_t)(kb_ + row) * DD + scol * 8);    \
      vreg[i] = *(const f32x4*)(Vg + (size_t)row * NN + kb_ + scol * 8);      \
    }                                                                         \
  }
#define STAGE_WRITE()                                                         \
  {                                                                           \
    _Pragma("unroll") for (int i = 0; i < 4; ++i) {                           \
      int row = i * 16 + sr8;                                                 \
      int swz = (scol * 16) ^ ((row & 7) << 4);                               \
      *(f32x4*)(Ks + row * 128 + swz) = kreg[i];                              \
      *(f32x4*)(Vs + row * 128 + swz) = vreg[i];                              \
    }                                                                         \
  }

  STAGE_LOAD(0);
  STAGE_WRITE();
  __syncthreads();

  for (int it = 0; it < 32; ++it) {
    if (it < 31) STAGE_LOAD(it + 1);

    // S^T = K_perm @ Q
    f32x4 s[4] = {};
#pragma unroll
    for (int t = 0; t < 4; ++t) {
      int krow = (t & 1) * 32 + ((llo >> 2) << 3) + ((t >> 1) << 2) + (llo & 3);
      int ksz = (krow & 7) << 4;
      const char* kp = Ks + krow * 128;
      s[t] = MFMA16(*(const bf16x8*)(kp + ((lhi * 16) ^ ksz)), qf[0], s[t]);
      s[t] = MFMA16(*(const bf16x8*)(kp + ((64 + lhi * 16) ^ ksz)), qf[1], s[t]);
    }

    // online softmax: lane owns one q; in-register max tree + 2 shfls
    float pm = s[0][0];
#pragma unroll
    for (int t = 0; t < 4; ++t)
#pragma unroll
      for (int r = 0; r < 4; ++r) pm = fmaxf(pm, s[t][r]);
    pm = fmaxf(pm, __shfl_xor(pm, 16));
    pm = fmaxf(pm, __shfl_xor(pm, 32));
    float mn = fmaxf(m, pm);
    float al = __expf(m - mn);
    m = mn;
    float ps = 0.f;
#pragma unroll
    for (int t = 0; t < 4; ++t)
#pragma unroll
      for (int r = 0; r < 4; ++r) {
        float p = __expf(s[t][r] - mn);
        s[t][r] = p;
        ps += p;
      }
    lsum = lsum * al + ps;
#pragma unroll
    for (int dt = 0; dt < 4; ++dt)
#pragma unroll
      for (int r = 0; r < 4; ++r) oacc[dt][r] *= al;

    // P -> PV B-fragments entirely in-lane (scalar f2bf packing)
    union { unsigned int u[4]; bf16x8 v; } F0, F1;
    F0.u[0] = pk2(s[0][0], s[0][1]); F0.u[1] = pk2(s[0][2], s[0][3]);
    F0.u[2] = pk2(s[2][0], s[2][1]); F0.u[3] = pk2(s[2][2], s[2][3]);
    F1.u[0] = pk2(s[1][0], s[1][1]); F1.u[1] = pk2(s[1][2], s[1][3]);
    F1.u[2] = pk2(s[3][0], s[3][1]); F1.u[3] = pk2(s[3][2], s[3][3]);

    // O^T += V^T @ P^T : oacc[dt] = O[q=llo][d = dt*16 + lhi*4 + r]
#pragma unroll
    for (int dt = 0; dt < 4; ++dt) {
      int vrow = dt * 16 + llo;
      int vsz = (vrow & 7) << 4;
      const char* vp = Vs + vrow * 128;
      oacc[dt] = MFMA16(*(const bf16x8*)(vp + ((lhi * 16) ^ vsz)), F0.v, oacc[dt]);
      oacc[dt] = MFMA16(*(const bf16x8*)(vp + ((64 + lhi * 16) ^ vsz)), F1.v, oacc[dt]);
    }

    __syncthreads();
    if (it < 31) STAGE_WRITE();
    __syncthreads();
  }

  // full row sum across the 4 lanes sharing q=llo
  lsum += __shfl_xor(lsum, 16);
  lsum += __shfl_xor(lsum, 32);

  // merge the two k-halves via LDS (reuse wk0's K/V region; barrier-separated)
  float* mO = (float*)ldsKV;             // [2][16][64] : (wq, q, d) from wk=1
  float* mM = (float*)(ldsKV + 8192);    // [2][16] running max
  float* mL = (float*)(ldsKV + 8192 + 128);
  if (wk == 1) {
#pragma unroll
    for (int dt = 0; dt < 4; ++dt)
#pragma unroll
      for (int r = 0; r < 4; ++r)
        mO[(wq * 16 + llo) * 64 + dt * 16 + lhi * 4 + r] = oacc[dt][r];
    if (lhi == 0) { mM[wq * 16 + llo] = m; mL[wq * 16 + llo] = lsum; }
  }
  __syncthreads();
  if (wk == 0) {
    float m2 = mM[wq * 16 + llo], l2 = mL[wq * 16 + llo];
    float mf = fmaxf(m, m2);
    float e1 = __expf(m - mf);
    float e2 = __expf(m2 - mf);
    float inv = 1.f / (lsum * e1 + l2 * e2);
    int qglob = qt * 32 + wq * 16 + llo;
    unsigned int* dst = (unsigned int*)(Ob + ((size_t)b * NN + qglob) * 128 + a * 64);
    const float* mOr = mO + (wq * 16 + llo) * 64;
#pragma unroll
    for (int dt = 0; dt < 4; ++dt) {
      int d0 = dt * 16 + lhi * 4;
      float v0 = (oacc[dt][0] * e1 + mOr[d0 + 0] * e2) * inv;
      float v1 = (oacc[dt][1] * e1 + mOr[d0 + 1] * e2) * inv;
      float v2 = (oacc[dt][2] * e1 + mOr[d0 + 2] * e2) * inv;
      float v3 = (oacc[dt][3] * e1 + mOr[d0 + 3] * e2) * inv;
      dst[dt * 8 + lhi * 2] = pk2(v0, v1);
      dst[dt * 8 + lhi * 2 + 1] = pk2(v2, v3);
    }
  }
}

// ---------------------------------------------------------------------------
// Kernel 5: OUT[b,c,n] = sum_d WO[c,d]*O[b,n,d] + BO[c] + x[b,c,n]
// ---------------------------------------------------------------------------
__global__ __launch_bounds__(256) void out_kernel(
    const unsigned short* __restrict__ Ob, const unsigned short* __restrict__ WO,
    const float* __restrict__ BO, const float* __restrict__ x,
    float* __restrict__ out)
{
  int nt = blockIdx.x;
  int ct = blockIdx.y;
  int b = blockIdx.z;
  int w = threadIdx.x >> 6, lane = threadIdx.x & 63;
  int lhi = lane >> 4, llo = lane & 15;
  int cb = ct * 64 + w * 16;

  f32x4 acc[4] = {};
#pragma unroll
  for (int kc = 0; kc < 4; ++kc) {
    bf16x8 af = *(const bf16x8*)(WO + (size_t)(cb + llo) * 128 + kc * 32 + lhi * 8);
#pragma unroll
    for (int nn = 0; nn < 4; ++nn) {
      bf16x8 bfr = *(const bf16x8*)(Ob + ((size_t)b * NN + nt * 64 + nn * 16 + llo) * 128 + kc * 32 + lhi * 8);
      acc[nn] = MFMA16(af, bfr, acc[nn]);
    }
  }
#pragma unroll
  for (int nn = 0; nn < 4; ++nn)
#pragma unroll
    for (int r = 0; r < 4; ++r) {
      int c = cb + lhi * 4 + r;
      int n = nt * 64 + nn * 16 + llo;
      size_t idx = ((size_t)b * CC + c) * NN + n;
      out[idx] = acc[nn][r] + BO[c] + x[idx];
    }
}

// ---------------------------------------------------------------------------
extern "C" void kernel_launch(void* const* d_in, const int* in_sizes, int n_in,
                              void* d_out, int out_size, void* d_ws, size_t ws_size,
                              hipStream_t stream) {
  const float* x = (const float*)d_in[0];
  const float* x1 = (const float*)d_in[1];
  const float* x2 = (const float*)d_in[2];
  const float* bn1_g = (const float*)d_in[3];
  const float* bn1_b = (const float*)d_in[4];
  const float* bn1_m = (const float*)d_in[5];
  const float* bn1_v = (const float*)d_in[6];
  const float* bn2_g = (const float*)d_in[7];
  const float* bn2_b = (const float*)d_in[8];
  const float* bn2_m = (const float*)d_in[9];
  const float* bn2_v = (const float*)d_in[10];
  const float* kq1_w = (const float*)d_in[11];
  const float* kq1_b = (const float*)d_in[12];
  const float* kq2_w = (const float*)d_in[13];
  const float* kq2_b = (const float*)d_in[14];
  const float* v_w = (const float*)d_in[15];
  const float* v_b = (const float*)d_in[16];
  const float* out_w = (const float*)d_in[17];
  const float* out_b = (const float*)d_in[18];
  const float* bnl_g = (const float*)d_in[19];
  const float* bnl_b = (const float*)d_in[20];
  const float* bnl_m = (const float*)d_in[21];
  const float* bnl_v = (const float*)d_in[22];
  const float* w_scale = (const float*)d_in[23];

  char* ws = (char*)d_ws;
  const size_t XT_SZ = (size_t)NB * NN * CC * 2;        // 8 MB each
  const size_t QKV_SZ = (size_t)NB * 2 * NN * DD * 2;   // 4 MB each
  size_t off = 0;
  unsigned short* XT0 = (unsigned short*)(ws + off); off += XT_SZ;
  unsigned short* XT1 = (unsigned short*)(ws + off); off += XT_SZ;
  unsigned short* XT2 = (unsigned short*)(ws + off); off += XT_SZ;
  unsigned short* Qb = (unsigned short*)(ws + off); off += QKV_SZ;
  unsigned short* Kb = (unsigned short*)(ws + off); off += QKV_SZ;
  unsigned short* Vt = (unsigned short*)(ws + off); off += QKV_SZ;
  unsigned short* Ob = (unsigned short*)(ws + off); off += (size_t)NB * NN * 128 * 2;
  unsigned short* W1 = (unsigned short*)(ws + off); off += 128 * CC * 2;
  unsigned short* W2 = (unsigned short*)(ws + off); off += 128 * CC * 2;
  unsigned short* WV = (unsigned short*)(ws + off); off += 128 * CC * 2;
  unsigned short* WO = (unsigned short*)(ws + off); off += CC * 128 * 2;
  float* B1 = (float*)(ws + off); off += 512;
  float* B2 = (float*)(ws + off); off += 512;
  float* BV = (float*)(ws + off); off += 512;
  float* BO = (float*)(ws + off); off += 1024;
  if (ws_size < off) return;  // loud failure: output stays poisoned

  prep_kernel<<<4, 256, 0, stream>>>(
      kq1_w, kq1_b, kq2_w, kq2_b, v_w, v_b, out_w, out_b,
      bn1_g, bn1_b, bn1_m, bn1_v, bn2_g, bn2_b, bn2_m, bn2_v,
      bnl_g, bnl_b, bnl_m, bnl_v, w_scale,
      W1, W2, WV, WO, B1, B2, BV, BO);

  conv_kernel<<<dim3(64, 4, 12), 256, 0, stream>>>(x, x1, x2, XT0, XT1, XT2);

  proj_kernel<<<dim3(64, 3, 4), 256, 0, stream>>>(
      XT0, XT1, XT2, W1, W2, WV, B1, B2, BV, Qb, Kb, Vt);

  attn_kernel<<<dim3(128, 2, 4), 256, 0, stream>>>(Qb, Kb, Vt, Ob);

  out_kernel<<<dim3(64, 4, 4), 256, 0, stream>>>(Ob, WO, BO, x, (float*)d_out);
}

// Round 5
// 150.159 us; speedup vs baseline: 1.3018x; 1.0290x over previous
//
#include <hip/hip_runtime.h>

typedef short bf16x8 __attribute__((ext_vector_type(8)));
typedef float f32x4 __attribute__((ext_vector_type(4)));
typedef float f32x2 __attribute__((ext_vector_type(2)));
typedef unsigned short u16x4 __attribute__((ext_vector_type(4)));
typedef unsigned short u16x2 __attribute__((ext_vector_type(2)));

#define MFMA16(A, B, C) __builtin_amdgcn_mfma_f32_16x16x32_bf16((A), (B), (C), 0, 0, 0)

static constexpr int NB = 4;       // batch
static constexpr int CC = 256;     // channels (INC1 == INC2)
static constexpr int NN = 4096;    // H*W
static constexpr int DD = 64;      // head dim

__device__ __forceinline__ unsigned short f2bf(float f) {
  unsigned int u = __builtin_bit_cast(unsigned int, f);
  u += 0x7fffu + ((u >> 16) & 1u);
  return (unsigned short)(u >> 16);
}

__device__ __forceinline__ unsigned int pk2(float lo, float hi) {
  return (unsigned int)f2bf(lo) | ((unsigned int)f2bf(hi) << 16);
}

// LDS 16B-slot swizzle: injective per 8-lane phase for K-perm reads (row bits
// 0,1,3 vary), V reads (bits 0,1,2 vary) and staging writes (bits 0,1,2).
__device__ __forceinline__ int swz16(int row) {
  return ((row & 3) | ((((row >> 2) ^ (row >> 3)) & 1) << 2)) << 4;
}

// ---------------------------------------------------------------------------
// Kernel 1: fold BN into projection weights (parallel: wave per row).
// ---------------------------------------------------------------------------
__global__ __launch_bounds__(256) void prep_kernel(
    const float* __restrict__ kq1_w, const float* __restrict__ kq1_b,
    const float* __restrict__ kq2_w, const float* __restrict__ kq2_b,
    const float* __restrict__ v_w,   const float* __restrict__ v_b,
    const float* __restrict__ out_w, const float* __restrict__ out_b,
    const float* __restrict__ bn1_g, const float* __restrict__ bn1_b,
    const float* __restrict__ bn1_m, const float* __restrict__ bn1_v,
    const float* __restrict__ bn2_g, const float* __restrict__ bn2_b,
    const float* __restrict__ bn2_m, const float* __restrict__ bn2_v,
    const float* __restrict__ bnl_g, const float* __restrict__ bnl_b,
    const float* __restrict__ bnl_m, const float* __restrict__ bnl_v,
    const float* __restrict__ w_scale,
    unsigned short* __restrict__ W1, unsigned short* __restrict__ W2,
    unsigned short* __restrict__ WV, unsigned short* __restrict__ WO,
    float* __restrict__ B1, float* __restrict__ B2,
    float* __restrict__ BV, float* __restrict__ BO)
{
  int blk = blockIdx.x;
  int tid = threadIdx.x;
  int w = tid >> 6, lane = tid & 63;
  if (blk < 3) {
    const float* Wsrc = blk == 0 ? kq1_w : (blk == 1 ? kq2_w : v_w);
    const float* bsrc = blk == 0 ? kq1_b : (blk == 1 ? kq2_b : v_b);
    unsigned short* Wdst = blk == 0 ? W1 : (blk == 1 ? W2 : WV);
    float* Bdst = blk == 0 ? B1 : (blk == 1 ? B2 : BV);
    __shared__ float s_lds[256], o_lds[256];
    if (blk == 0) {
      float s = bn1_g[tid] * rsqrtf(bn1_v[tid] + 1e-5f);
      s_lds[tid] = s;
      o_lds[tid] = bn1_b[tid] - bn1_m[tid] * s;
    } else if (blk == 1) {
      float s = bn2_g[tid] * rsqrtf(bn2_v[tid] + 1e-5f);
      s_lds[tid] = s;
      o_lds[tid] = bn2_b[tid] - bn2_m[tid] * s;
    } else {
      s_lds[tid] = 1.f;
      o_lds[tid] = 0.f;
    }
    __syncthreads();
    int c = lane * 4;
    for (int row = w; row < 128; row += 4) {
      f32x4 wv = *(const f32x4*)(Wsrc + row * CC + c);
      u16x4 o;
      float bacc = 0.f;
#pragma unroll
      for (int j = 0; j < 4; ++j) {
        o[j] = f2bf(wv[j] * s_lds[c + j]);
        bacc += wv[j] * o_lds[c + j];
      }
      *(u16x4*)(Wdst + row * CC + c) = o;
#pragma unroll
      for (int off = 1; off < 64; off <<= 1) bacc += __shfl_xor(bacc, off);
      if (lane == 0) Bdst[row] = bsrc[row] + bacc;
    }
  } else {
    float ws = w_scale[0];
    {
      float s = bnl_g[tid] * rsqrtf(bnl_v[tid] + 1e-5f);
      BO[tid] = ws * (out_b[tid] * s + bnl_b[tid] - bnl_m[tid] * s);
    }
    int d = lane * 2;
    for (int row = w; row < 256; row += 4) {
      float s = ws * bnl_g[row] * rsqrtf(bnl_v[row] + 1e-5f);
      f32x2 wv = *(const f32x2*)(out_w + row * 128 + d);
      u16x2 o;
      o[0] = f2bf(s * wv[0]);
      o[1] = f2bf(s * wv[1]);
      *(u16x2*)(WO + row * 128 + d) = o;
    }
  }
}

// ---------------------------------------------------------------------------
// Kernel 2: NCHW f32 -> (b, n, c) bf16 transpose-cast via LDS 64x64 tiles.
// ---------------------------------------------------------------------------
__global__ __launch_bounds__(256) void conv_kernel(
    const float* __restrict__ x, const float* __restrict__ x1, const float* __restrict__ x2,
    unsigned short* __restrict__ t0, unsigned short* __restrict__ t1, unsigned short* __restrict__ t2)
{
  int tensor = blockIdx.z >> 2, b = blockIdx.z & 3;
  const float* src = tensor == 0 ? x : (tensor == 1 ? x1 : x2);
  unsigned short* dst = tensor == 0 ? t0 : (tensor == 1 ? t1 : t2);
  int cb = blockIdx.y * 64, nb = blockIdx.x * 64;
  __shared__ float tile[64][65];
  int t = threadIdx.x;
  int cl = t >> 2, n0 = (t & 3) * 16;
  const float* s = src + ((size_t)b * CC + cb + cl) * NN + nb + n0;
  f32x4 v0 = *(const f32x4*)(s);
  f32x4 v1 = *(const f32x4*)(s + 4);
  f32x4 v2 = *(const f32x4*)(s + 8);
  f32x4 v3 = *(const f32x4*)(s + 12);
#pragma unroll
  for (int j = 0; j < 4; ++j) {
    tile[cl][n0 + j] = v0[j];
    tile[cl][n0 + 4 + j] = v1[j];
    tile[cl][n0 + 8 + j] = v2[j];
    tile[cl][n0 + 12 + j] = v3[j];
  }
  __syncthreads();
  int nl = t >> 2, c0 = (t & 3) * 16;
  unsigned short* d = dst + ((size_t)b * NN + nb + nl) * CC + cb + c0;
  alignas(16) unsigned short tmp[16];
#pragma unroll
  for (int j = 0; j < 16; ++j) tmp[j] = f2bf(tile[c0 + j][nl]);
  *(bf16x8*)(d) = *(const bf16x8*)(tmp);
  *(bf16x8*)(d + 8) = *(const bf16x8*)(tmp + 8);
}

// ---------------------------------------------------------------------------
// Kernel 3: projections. Q pre-scaled by 1/sqrt(64)=0.125 (natural-exp domain).
// ---------------------------------------------------------------------------
__global__ __launch_bounds__(256) void proj_kernel(
    const unsigned short* __restrict__ Xt0, const unsigned short* __restrict__ Xt1,
    const unsigned short* __restrict__ Xt2,
    const unsigned short* __restrict__ W1, const unsigned short* __restrict__ W2,
    const unsigned short* __restrict__ WV,
    const float* __restrict__ B1, const float* __restrict__ B2, const float* __restrict__ BV,
    unsigned short* __restrict__ Qb, unsigned short* __restrict__ Kb,
    unsigned short* __restrict__ Vt)
{
  int nt = blockIdx.x;
  int mat = blockIdx.y;
  int b = blockIdx.z;
  const unsigned short* X =
      (mat == 0 ? Xt1 : (mat == 1 ? Xt2 : Xt0)) + (size_t)b * NN * CC;
  const unsigned short* W = mat == 0 ? W1 : (mat == 1 ? W2 : WV);
  const float* Bi = mat == 0 ? B1 : (mat == 1 ? B2 : BV);
  int w = threadIdx.x >> 6, lane = threadIdx.x & 63;
  int lhi = lane >> 4, llo = lane & 15;
  int ob = w * 32;

  f32x4 acc[2][4] = {};
#pragma unroll
  for (int kc = 0; kc < 8; ++kc) {
    bf16x8 af[2], bfr[4];
#pragma unroll
    for (int ot = 0; ot < 2; ++ot)
      af[ot] = *(const bf16x8*)(W + (size_t)(ob + ot * 16 + llo) * CC + kc * 32 + lhi * 8);
#pragma unroll
    for (int nn = 0; nn < 4; ++nn)
      bfr[nn] = *(const bf16x8*)(X + ((size_t)nt * 64 + nn * 16 + llo) * CC + kc * 32 + lhi * 8);
#pragma unroll
    for (int ot = 0; ot < 2; ++ot)
#pragma unroll
      for (int nn = 0; nn < 4; ++nn)
        acc[ot][nn] = MFMA16(af[ot], bfr[nn], acc[ot][nn]);
  }

#pragma unroll
  for (int ot = 0; ot < 2; ++ot)
#pragma unroll
    for (int nn = 0; nn < 4; ++nn)
#pragma unroll
      for (int r = 0; r < 4; ++r) {
        int o = ob + ot * 16 + lhi * 4 + r;
        int n = nt * 64 + nn * 16 + llo;
        float val = acc[ot][nn][r] + Bi[o];
        if (mat < 2) {
          int blk = o >> 5;              // 0:K a0  1:Q a0  2:K a1  3:Q a1
          int aa = blk >> 1;
          int d = (o & 31) + mat * 32;
          if (blk & 1) val *= 0.125f;
          unsigned short* dstp = (blk & 1) ? Qb : Kb;
          dstp[((size_t)(b * 2 + aa) * NN + n) * DD + d] = f2bf(val);
        } else {
          int aa = o >> 6, d = o & 63;
          Vt[((size_t)(b * 2 + aa) * DD + d) * NN + n] = f2bf(val);
        }
      }
}

// ---------------------------------------------------------------------------
// Kernel 4: flash attention, swapped-QK^T (R4-verified) + conflict-free
// swizzle + exact defer-rescale + tree reductions + setprio.
// ---------------------------------------------------------------------------
__global__ __launch_bounds__(256, 4) void attn_kernel(
    const unsigned short* __restrict__ Qb, const unsigned short* __restrict__ Kb,
    const unsigned short* __restrict__ Vt, unsigned short* __restrict__ Ob)
{
  int qt = blockIdx.x;
  int a = blockIdx.y;
  int b = blockIdx.z;
  int ba = b * 2 + a;
  int tid = threadIdx.x;
  int w = tid >> 6;
  int lane = tid & 63;
  int lhi = lane >> 4, llo = lane & 15;
  int wq = w & 1, wk = w >> 1;

  __shared__ char ldsKV[32768];          // [wk][ K 8KB | V 8KB ]
  char* Ks = ldsKV + wk * 16384;
  char* Vs = Ks + 8192;

  // Q as B-operand: lane (llo,lhi) holds Q[q=llo][d = h*32 + lhi*8 ..+8]
  const unsigned short* Qg = Qb + ((size_t)ba * NN + qt * 32 + wq * 16) * DD;
  bf16x8 qf[2];
  qf[0] = *(const bf16x8*)(Qg + (size_t)llo * DD + lhi * 8);
  qf[1] = *(const bf16x8*)(Qg + (size_t)llo * DD + 32 + lhi * 8);

  const unsigned short* Kg = Kb + ((size_t)ba * NN + wk * 2048) * DD;
  const unsigned short* Vg = Vt + (size_t)ba * DD * NN + wk * 2048;

  f32x4 oacc[4] = {};
  float m = -1e30f, lsum = 0.f;

  // staging: 128 threads per k-half stream; (row, 16B-slot) per thread x4
  int t7 = tid & 127;
  int sr8 = t7 >> 3, scol = t7 & 7;

  f32x4 kreg[4], vreg[4];
#define STAGE_LOAD(IT)                                                        \
  {                                                                           \
    int kb_ = (IT) * 64;                                                      \
    _Pragma("unroll") for (int i = 0; i < 4; ++i) {                           \
      int row = i * 16 + sr8;                                                 \
      kreg[i] = *(const f32x4*)(Kg + (size_t)(kb_ + row) * DD + scol * 8);    \
      vreg[i] = *(const f32x4*)(Vg + (size_t)row * NN + kb_ + scol * 8);      \
    }                                                                         \
  }
#define STAGE_WRITE()                                                         \
  {                                                                           \
    _Pragma("unroll") for (int i = 0; i < 4; ++i) {                           \
      int row = i * 16 + sr8;                                                 \
      int swz = (scol * 16) ^ swz16(row);                                     \
      *(f32x4*)(Ks + row * 128 + swz) = kreg[i];                              \
      *(f32x4*)(Vs + row * 128 + swz) = vreg[i];                              \
    }                                                                         \
  }

  STAGE_LOAD(0);
  STAGE_WRITE();
  __syncthreads();

  for (int it = 0; it < 32; ++it) {
    if (it < 31) STAGE_LOAD(it + 1);

    // S^T = K_perm @ Q
    f32x4 s[4] = {};
    __builtin_amdgcn_s_setprio(1);
#pragma unroll
    for (int t = 0; t < 4; ++t) {
      int krow = (t & 1) * 32 + ((llo >> 2) << 3) + ((t >> 1) << 2) + (llo & 3);
      int ksz = swz16(krow);
      const char* kp = Ks + krow * 128;
      s[t] = MFMA16(*(const bf16x8*)(kp + ((lhi * 16) ^ ksz)), qf[0], s[t]);
      s[t] = MFMA16(*(const bf16x8*)(kp + ((64 + lhi * 16) ^ ksz)), qf[1], s[t]);
    }
    __builtin_amdgcn_s_setprio(0);

    // online softmax: lane owns one q; tree max + 2 shfls
    float t0 = fmaxf(fmaxf(s[0][0], s[0][1]), fmaxf(s[0][2], s[0][3]));
    float t1 = fmaxf(fmaxf(s[1][0], s[1][1]), fmaxf(s[1][2], s[1][3]));
    float t2 = fmaxf(fmaxf(s[2][0], s[2][1]), fmaxf(s[2][2], s[2][3]));
    float t3 = fmaxf(fmaxf(s[3][0], s[3][1]), fmaxf(s[3][2], s[3][3]));
    float pm = fmaxf(fmaxf(t0, t1), fmaxf(t2, t3));
    pm = fmaxf(pm, __shfl_xor(pm, 16));
    pm = fmaxf(pm, __shfl_xor(pm, 32));
    if (__any(pm > m)) {       // exact skip: pm<=m everywhere => al==1
      float mn = fmaxf(m, pm);
      float al = __expf(m - mn);
      m = mn;
      lsum *= al;
#pragma unroll
      for (int dt = 0; dt < 4; ++dt)
#pragma unroll
        for (int r = 0; r < 4; ++r) oacc[dt][r] *= al;
    }
#pragma unroll
    for (int t = 0; t < 4; ++t)
#pragma unroll
      for (int r = 0; r < 4; ++r) s[t][r] = __expf(s[t][r] - m);
    float p0 = (s[0][0] + s[0][1]) + (s[0][2] + s[0][3]);
    float p1 = (s[1][0] + s[1][1]) + (s[1][2] + s[1][3]);
    float p2 = (s[2][0] + s[2][1]) + (s[2][2] + s[2][3]);
    float p3 = (s[3][0] + s[3][1]) + (s[3][2] + s[3][3]);
    lsum += (p0 + p1) + (p2 + p3);

    // P -> PV B-fragments entirely in-lane (scalar f2bf packing)
    union { unsigned int u[4]; bf16x8 v; } F0, F1;
    F0.u[0] = pk2(s[0][0], s[0][1]); F0.u[1] = pk2(s[0][2], s[0][3]);
    F0.u[2] = pk2(s[2][0], s[2][1]); F0.u[3] = pk2(s[2][2], s[2][3]);
    F1.u[0] = pk2(s[1][0], s[1][1]); F1.u[1] = pk2(s[1][2], s[1][3]);
    F1.u[2] = pk2(s[3][0], s[3][1]); F1.u[3] = pk2(s[3][2], s[3][3]);

    // O^T += V^T @ P^T : oacc[dt] = O[q=llo][d = dt*16 + lhi*4 + r]
    __builtin_amdgcn_s_setprio(1);
#pragma unroll
    for (int dt = 0; dt < 4; ++dt) {
      int vrow = dt * 16 + llo;
      int vsz = swz16(vrow);
      const char* vp = Vs + vrow * 128;
      oacc[dt] = MFMA16(*(const bf16x8*)(vp + ((lhi * 16) ^ vsz)), F0.v, oacc[dt]);
      oacc[dt] = MFMA16(*(const bf16x8*)(vp + ((64 + lhi * 16) ^ vsz)), F1.v, oacc[dt]);
    }
    __builtin_amdgcn_s_setprio(0);

    __syncthreads();
    if (it < 31) STAGE_WRITE();
    __syncthreads();
  }

  // full row sum across the 4 lanes sharing q=llo
  lsum += __shfl_xor(lsum, 16);
  lsum += __shfl_xor(lsum, 32);

  // merge the two k-halves via LDS (reuse wk0's K/V region; barrier-separated)
  float* mO = (float*)ldsKV;             // [2][16][64] : (wq, q, d) from wk=1
  float* mM = (float*)(ldsKV + 8192);    // [2][16] running max
  float* mL = (float*)(ldsKV + 8192 + 128);
  if (wk == 1) {
#pragma unroll
    for (int dt = 0; dt < 4; ++dt)
#pragma unroll
      for (int r = 0; r < 4; ++r)
        mO[(wq * 16 + llo) * 64 + dt * 16 + lhi * 4 + r] = oacc[dt][r];
    if (lhi == 0) { mM[wq * 16 + llo] = m; mL[wq * 16 + llo] = lsum; }
  }
  __syncthreads();
  if (wk == 0) {
    float m2 = mM[wq * 16 + llo], l2 = mL[wq * 16 + llo];
    float mf = fmaxf(m, m2);
    float e1 = __expf(m - mf);
    float e2 = __expf(m2 - mf);
    float inv = 1.f / (lsum * e1 + l2 * e2);
    int qglob = qt * 32 + wq * 16 + llo;
    unsigned int* dst = (unsigned int*)(Ob + ((size_t)b * NN + qglob) * 128 + a * 64);
    const float* mOr = mO + (wq * 16 + llo) * 64;
#pragma unroll
    for (int dt = 0; dt < 4; ++dt) {
      int d0 = dt * 16 + lhi * 4;
      float v0 = (oacc[dt][0] * e1 + mOr[d0 + 0] * e2) * inv;
      float v1 = (oacc[dt][1] * e1 + mOr[d0 + 1] * e2) * inv;
      float v2 = (oacc[dt][2] * e1 + mOr[d0 + 2] * e2) * inv;
      float v3 = (oacc[dt][3] * e1 + mOr[d0 + 3] * e2) * inv;
      dst[dt * 8 + lhi * 2] = pk2(v0, v1);
      dst[dt * 8 + lhi * 2 + 1] = pk2(v2, v3);
    }
  }
}

// ---------------------------------------------------------------------------
// Kernel 5: OUT[b,c,n] = sum_d WO[c,d]*O[b,n,d] + BO[c] + x[b,c,n]
// ---------------------------------------------------------------------------
__global__ __launch_bounds__(256) void out_kernel(
    const unsigned short* __restrict__ Ob, const unsigned short* __restrict__ WO,
    const float* __restrict__ BO, const float* __restrict__ x,
    float* __restrict__ out)
{
  int nt = blockIdx.x;
  int ct = blockIdx.y;
  int b = blockIdx.z;
  int w = threadIdx.x >> 6, lane = threadIdx.x & 63;
  int lhi = lane >> 4, llo = lane & 15;
  int cb = ct * 64 + w * 16;

  f32x4 acc[4] = {};
#pragma unroll
  for (int kc = 0; kc < 4; ++kc) {
    bf16x8 af = *(const bf16x8*)(WO + (size_t)(cb + llo) * 128 + kc * 32 + lhi * 8);
#pragma unroll
    for (int nn = 0; nn < 4; ++nn) {
      bf16x8 bfr = *(const bf16x8*)(Ob + ((size_t)b * NN + nt * 64 + nn * 16 + llo) * 128 + kc * 32 + lhi * 8);
      acc[nn] = MFMA16(af, bfr, acc[nn]);
    }
  }
#pragma unroll
  for (int nn = 0; nn < 4; ++nn)
#pragma unroll
    for (int r = 0; r < 4; ++r) {
      int c = cb + lhi * 4 + r;
      int n = nt * 64 + nn * 16 + llo;
      size_t idx = ((size_t)b * CC + c) * NN + n;
      out[idx] = acc[nn][r] + BO[c] + x[idx];
    }
}

// ---------------------------------------------------------------------------
extern "C" void kernel_launch(void* const* d_in, const int* in_sizes, int n_in,
                              void* d_out, int out_size, void* d_ws, size_t ws_size,
                              hipStream_t stream) {
  const float* x = (const float*)d_in[0];
  const float* x1 = (const float*)d_in[1];
  const float* x2 = (const float*)d_in[2];
  const float* bn1_g = (const float*)d_in[3];
  const float* bn1_b = (const float*)d_in[4];
  const float* bn1_m = (const float*)d_in[5];
  const float* bn1_v = (const float*)d_in[6];
  const float* bn2_g = (const float*)d_in[7];
  const float* bn2_b = (const float*)d_in[8];
  const float* bn2_m = (const float*)d_in[9];
  const float* bn2_v = (const float*)d_in[10];
  const float* kq1_w = (const float*)d_in[11];
  const float* kq1_b = (const float*)d_in[12];
  const float* kq2_w = (const float*)d_in[13];
  const float* kq2_b = (const float*)d_in[14];
  const float* v_w = (const float*)d_in[15];
  const float* v_b = (const float*)d_in[16];
  const float* out_w = (const float*)d_in[17];
  const float* out_b = (const float*)d_in[18];
  const float* bnl_g = (const float*)d_in[19];
  const float* bnl_b = (const float*)d_in[20];
  const float* bnl_m = (const float*)d_in[21];
  const float* bnl_v = (const float*)d_in[22];
  const float* w_scale = (const float*)d_in[23];

  char* ws = (char*)d_ws;
  const size_t XT_SZ = (size_t)NB * NN * CC * 2;        // 8 MB each
  const size_t QKV_SZ = (size_t)NB * 2 * NN * DD * 2;   // 4 MB each
  size_t off = 0;
  unsigned short* XT0 = (unsigned short*)(ws + off); off += XT_SZ;
  unsigned short* XT1 = (unsigned short*)(ws + off); off += XT_SZ;
  unsigned short* XT2 = (unsigned short*)(ws + off); off += XT_SZ;
  unsigned short* Qb = (unsigned short*)(ws + off); off += QKV_SZ;
  unsigned short* Kb = (unsigned short*)(ws + off); off += QKV_SZ;
  unsigned short* Vt = (unsigned short*)(ws + off); off += QKV_SZ;
  unsigned short* Ob = (unsigned short*)(ws + off); off += (size_t)NB * NN * 128 * 2;
  unsigned short* W1 = (unsigned short*)(ws + off); off += 128 * CC * 2;
  unsigned short* W2 = (unsigned short*)(ws + off); off += 128 * CC * 2;
  unsigned short* WV = (unsigned short*)(ws + off); off += 128 * CC * 2;
  unsigned short* WO = (unsigned short*)(ws + off); off += CC * 128 * 2;
  float* B1 = (float*)(ws + off); off += 512;
  float* B2 = (float*)(ws + off); off += 512;
  float* BV = (float*)(ws + off); off += 512;
  float* BO = (float*)(ws + off); off += 1024;
  if (ws_size < off) return;  // loud failure: output stays poisoned

  prep_kernel<<<4, 256, 0, stream>>>(
      kq1_w, kq1_b, kq2_w, kq2_b, v_w, v_b, out_w, out_b,
      bn1_g, bn1_b, bn1_m, bn1_v, bn2_g, bn2_b, bn2_m, bn2_v,
      bnl_g, bnl_b, bnl_m, bnl_v, w_scale,
      W1, W2, WV, WO, B1, B2, BV, BO);

  conv_kernel<<<dim3(64, 4, 12), 256, 0, stream>>>(x, x1, x2, XT0, XT1, XT2);

  proj_kernel<<<dim3(64, 3, 4), 256, 0, stream>>>(
      XT0, XT1, XT2, W1, W2, WV, B1, B2, BV, Qb, Kb, Vt);

  attn_kernel<<<dim3(128, 2, 4), 256, 0, stream>>>(Qb, Kb, Vt, Ob);

  out_kernel<<<dim3(64, 4, 4), 256, 0, stream>>>(Ob, WO, BO, x, (float*)d_out);
}

// Round 6
// 146.617 us; speedup vs baseline: 1.3332x; 1.0242x over previous
//
#include <hip/hip_runtime.h>

typedef short bf16x8 __attribute__((ext_vector_type(8)));
typedef float f32x4 __attribute__((ext_vector_type(4)));
typedef float f32x2 __attribute__((ext_vector_type(2)));
typedef unsigned short u16x4 __attribute__((ext_vector_type(4)));
typedef unsigned short u16x2 __attribute__((ext_vector_type(2)));

#define MFMA16(A, B, C) __builtin_amdgcn_mfma_f32_16x16x32_bf16((A), (B), (C), 0, 0, 0)

static constexpr int NB = 4;       // batch
static constexpr int CC = 256;     // channels (INC1 == INC2)
static constexpr int NN = 4096;    // H*W
static constexpr int DD = 64;      // head dim

__device__ __forceinline__ unsigned short f2bf(float f) {
  unsigned int u = __builtin_bit_cast(unsigned int, f);
  u += 0x7fffu + ((u >> 16) & 1u);
  return (unsigned short)(u >> 16);
}

__device__ __forceinline__ unsigned int pk2(float lo, float hi) {
  return (unsigned int)f2bf(lo) | ((unsigned int)f2bf(hi) << 16);
}

// LDS 16B-slot swizzle (R5-verified)
__device__ __forceinline__ int swz16(int row) {
  return ((row & 3) | ((((row >> 2) ^ (row >> 3)) & 1) << 2)) << 4;
}

// ---------------------------------------------------------------------------
// Kernel 1: fold BN into projection weights (parallel: wave per row).
// ---------------------------------------------------------------------------
__global__ __launch_bounds__(256) void prep_kernel(
    const float* __restrict__ kq1_w, const float* __restrict__ kq1_b,
    const float* __restrict__ kq2_w, const float* __restrict__ kq2_b,
    const float* __restrict__ v_w,   const float* __restrict__ v_b,
    const float* __restrict__ out_w, const float* __restrict__ out_b,
    const float* __restrict__ bn1_g, const float* __restrict__ bn1_b,
    const float* __restrict__ bn1_m, const float* __restrict__ bn1_v,
    const float* __restrict__ bn2_g, const float* __restrict__ bn2_b,
    const float* __restrict__ bn2_m, const float* __restrict__ bn2_v,
    const float* __restrict__ bnl_g, const float* __restrict__ bnl_b,
    const float* __restrict__ bnl_m, const float* __restrict__ bnl_v,
    const float* __restrict__ w_scale,
    unsigned short* __restrict__ W1, unsigned short* __restrict__ W2,
    unsigned short* __restrict__ WV, unsigned short* __restrict__ WO,
    float* __restrict__ B1, float* __restrict__ B2,
    float* __restrict__ BV, float* __restrict__ BO)
{
  int blk = blockIdx.x;
  int tid = threadIdx.x;
  int w = tid >> 6, lane = tid & 63;
  if (blk < 3) {
    const float* Wsrc = blk == 0 ? kq1_w : (blk == 1 ? kq2_w : v_w);
    const float* bsrc = blk == 0 ? kq1_b : (blk == 1 ? kq2_b : v_b);
    unsigned short* Wdst = blk == 0 ? W1 : (blk == 1 ? W2 : WV);
    float* Bdst = blk == 0 ? B1 : (blk == 1 ? B2 : BV);
    __shared__ float s_lds[256], o_lds[256];
    if (blk == 0) {
      float s = bn1_g[tid] * rsqrtf(bn1_v[tid] + 1e-5f);
      s_lds[tid] = s;
      o_lds[tid] = bn1_b[tid] - bn1_m[tid] * s;
    } else if (blk == 1) {
      float s = bn2_g[tid] * rsqrtf(bn2_v[tid] + 1e-5f);
      s_lds[tid] = s;
      o_lds[tid] = bn2_b[tid] - bn2_m[tid] * s;
    } else {
      s_lds[tid] = 1.f;
      o_lds[tid] = 0.f;
    }
    __syncthreads();
    int c = lane * 4;
    for (int row = w; row < 128; row += 4) {
      f32x4 wv = *(const f32x4*)(Wsrc + row * CC + c);
      u16x4 o;
      float bacc = 0.f;
#pragma unroll
      for (int j = 0; j < 4; ++j) {
        o[j] = f2bf(wv[j] * s_lds[c + j]);
        bacc += wv[j] * o_lds[c + j];
      }
      *(u16x4*)(Wdst + row * CC + c) = o;
#pragma unroll
      for (int off = 1; off < 64; off <<= 1) bacc += __shfl_xor(bacc, off);
      if (lane == 0) Bdst[row] = bsrc[row] + bacc;
    }
  } else {
    float ws = w_scale[0];
    {
      float s = bnl_g[tid] * rsqrtf(bnl_v[tid] + 1e-5f);
      BO[tid] = ws * (out_b[tid] * s + bnl_b[tid] - bnl_m[tid] * s);
    }
    int d = lane * 2;
    for (int row = w; row < 256; row += 4) {
      float s = ws * bnl_g[row] * rsqrtf(bnl_v[row] + 1e-5f);
      f32x2 wv = *(const f32x2*)(out_w + row * 128 + d);
      u16x2 o;
      o[0] = f2bf(s * wv[0]);
      o[1] = f2bf(s * wv[1]);
      *(u16x2*)(WO + row * 128 + d) = o;
    }
  }
}

// ---------------------------------------------------------------------------
// Kernel 2: NCHW f32 -> (b, n, c) bf16 transpose-cast via LDS 64x64 tiles.
// ---------------------------------------------------------------------------
__global__ __launch_bounds__(256) void conv_kernel(
    const float* __restrict__ x, const float* __restrict__ x1, const float* __restrict__ x2,
    unsigned short* __restrict__ t0, unsigned short* __restrict__ t1, unsigned short* __restrict__ t2)
{
  int tensor = blockIdx.z >> 2, b = blockIdx.z & 3;
  const float* src = tensor == 0 ? x : (tensor == 1 ? x1 : x2);
  unsigned short* dst = tensor == 0 ? t0 : (tensor == 1 ? t1 : t2);
  int cb = blockIdx.y * 64, nb = blockIdx.x * 64;
  __shared__ float tile[64][65];
  int t = threadIdx.x;
  int cl = t >> 2, n0 = (t & 3) * 16;
  const float* s = src + ((size_t)b * CC + cb + cl) * NN + nb + n0;
  f32x4 v0 = *(const f32x4*)(s);
  f32x4 v1 = *(const f32x4*)(s + 4);
  f32x4 v2 = *(const f32x4*)(s + 8);
  f32x4 v3 = *(const f32x4*)(s + 12);
#pragma unroll
  for (int j = 0; j < 4; ++j) {
    tile[cl][n0 + j] = v0[j];
    tile[cl][n0 + 4 + j] = v1[j];
    tile[cl][n0 + 8 + j] = v2[j];
    tile[cl][n0 + 12 + j] = v3[j];
  }
  __syncthreads();
  int nl = t >> 2, c0 = (t & 3) * 16;
  unsigned short* d = dst + ((size_t)b * NN + nb + nl) * CC + cb + c0;
  alignas(16) unsigned short tmp[16];
#pragma unroll
  for (int j = 0; j < 16; ++j) tmp[j] = f2bf(tile[c0 + j][nl]);
  *(bf16x8*)(d) = *(const bf16x8*)(tmp);
  *(bf16x8*)(d + 8) = *(const bf16x8*)(tmp + 8);
}

// ---------------------------------------------------------------------------
// Kernel 3: projections. Q pre-scaled by 1/sqrt(64)=0.125 (natural-exp domain).
// ---------------------------------------------------------------------------
__global__ __launch_bounds__(256) void proj_kernel(
    const unsigned short* __restrict__ Xt0, const unsigned short* __restrict__ Xt1,
    const unsigned short* __restrict__ Xt2,
    const unsigned short* __restrict__ W1, const unsigned short* __restrict__ W2,
    const unsigned short* __restrict__ WV,
    const float* __restrict__ B1, const float* __restrict__ B2, const float* __restrict__ BV,
    unsigned short* __restrict__ Qb, unsigned short* __restrict__ Kb,
    unsigned short* __restrict__ Vt)
{
  int nt = blockIdx.x;
  int mat = blockIdx.y;
  int b = blockIdx.z;
  const unsigned short* X =
      (mat == 0 ? Xt1 : (mat == 1 ? Xt2 : Xt0)) + (size_t)b * NN * CC;
  const unsigned short* W = mat == 0 ? W1 : (mat == 1 ? W2 : WV);
  const float* Bi = mat == 0 ? B1 : (mat == 1 ? B2 : BV);
  int w = threadIdx.x >> 6, lane = threadIdx.x & 63;
  int lhi = lane >> 4, llo = lane & 15;
  int ob = w * 32;

  f32x4 acc[2][4] = {};
#pragma unroll
  for (int kc = 0; kc < 8; ++kc) {
    bf16x8 af[2], bfr[4];
#pragma unroll
    for (int ot = 0; ot < 2; ++ot)
      af[ot] = *(const bf16x8*)(W + (size_t)(ob + ot * 16 + llo) * CC + kc * 32 + lhi * 8);
#pragma unroll
    for (int nn = 0; nn < 4; ++nn)
      bfr[nn] = *(const bf16x8*)(X + ((size_t)nt * 64 + nn * 16 + llo) * CC + kc * 32 + lhi * 8);
#pragma unroll
    for (int ot = 0; ot < 2; ++ot)
#pragma unroll
      for (int nn = 0; nn < 4; ++nn)
        acc[ot][nn] = MFMA16(af[ot], bfr[nn], acc[ot][nn]);
  }

#pragma unroll
  for (int ot = 0; ot < 2; ++ot)
#pragma unroll
    for (int nn = 0; nn < 4; ++nn)
#pragma unroll
      for (int r = 0; r < 4; ++r) {
        int o = ob + ot * 16 + lhi * 4 + r;
        int n = nt * 64 + nn * 16 + llo;
        float val = acc[ot][nn][r] + Bi[o];
        if (mat < 2) {
          int blk = o >> 5;              // 0:K a0  1:Q a0  2:K a1  3:Q a1
          int aa = blk >> 1;
          int d = (o & 31) + mat * 32;
          if (blk & 1) val *= 0.125f;
          unsigned short* dstp = (blk & 1) ? Qb : Kb;
          dstp[((size_t)(b * 2 + aa) * NN + n) * DD + d] = f2bf(val);
        } else {
          int aa = o >> 6, d = o & 63;
          Vt[((size_t)(b * 2 + aa) * DD + d) * NN + n] = f2bf(val);
        }
      }
}

// ---------------------------------------------------------------------------
// Kernel 4: flash attention, swapped-QK^T, 32 q-rows per wave (2 qh
// sub-fragments sharing each K/V LDS read), double-buffered K/V with ONE
// barrier per iter. Block = 64 q (2 wq x 2 wk), wk = 2048-k half.
// ---------------------------------------------------------------------------
__global__ __launch_bounds__(256, 2) void attn_kernel(
    const unsigned short* __restrict__ Qb, const unsigned short* __restrict__ Kb,
    const unsigned short* __restrict__ Vt, unsigned short* __restrict__ Ob)
{
  int qt = blockIdx.x;                  // 64-q tile
  int a = blockIdx.y;
  int b = blockIdx.z;
  int ba = b * 2 + a;
  int tid = threadIdx.x;
  int w = tid >> 6;
  int lane = tid & 63;
  int lhi = lane >> 4, llo = lane & 15;
  int wq = w & 1, wk = w >> 1;

  __shared__ char lds[65536];           // [wk][buf][ K 8KB | V 8KB ]

  // Q as B-operand: qf[qh][h], lane holds Q[q = qh*16+llo][d = h*32+lhi*8..+8]
  const unsigned short* Qg = Qb + ((size_t)ba * NN + qt * 64 + wq * 32) * DD;
  bf16x8 qf[2][2];
#pragma unroll
  for (int qh = 0; qh < 2; ++qh)
#pragma unroll
    for (int h = 0; h < 2; ++h)
      qf[qh][h] = *(const bf16x8*)(Qg + (size_t)(qh * 16 + llo) * DD + h * 32 + lhi * 8);

  const unsigned short* Kg = Kb + ((size_t)ba * NN + wk * 2048) * DD;
  const unsigned short* Vg = Vt + (size_t)ba * DD * NN + wk * 2048;

  f32x4 oacc[2][4] = {};
  float m[2] = {-1e30f, -1e30f}, lsum[2] = {0.f, 0.f};

  // staging: 128 threads per wk half; (row, 16B-slot) per thread x4
  int t7 = tid & 127;
  int sr8 = t7 >> 3, scol = t7 & 7;

  f32x4 kreg[4], vreg[4];
#define STAGE_LOAD(IT)                                                        \
  {                                                                           \
    int kb_ = (IT) * 64;                                                      \
    _Pragma("unroll") for (int i = 0; i < 4; ++i) {                           \
      int row = i * 16 + sr8;                                                 \
      kreg[i] = *(const f32x4*)(Kg + (size_t)(kb_ + row) * DD + scol * 8);    \
      vreg[i] = *(const f32x4*)(Vg + (size_t)row * NN + kb_ + scol * 8);      \
    }                                                                         \
  }
#define STAGE_WRITE(BUF)                                                      \
  {                                                                           \
    char* base_ = lds + wk * 32768 + (BUF) * 16384;                           \
    _Pragma("unroll") for (int i = 0; i < 4; ++i) {                           \
      int row = i * 16 + sr8;                                                 \
      int swz = (scol * 16) ^ swz16(row);                                     \
      *(f32x4*)(base_ + row * 128 + swz) = kreg[i];                           \
      *(f32x4*)(base_ + 8192 + row * 128 + swz) = vreg[i];                    \
    }                                                                         \
  }

  STAGE_LOAD(0);
  STAGE_WRITE(0);
  __syncthreads();

  int cur = 0;
  for (int it = 0; it < 32; ++it) {
    if (it < 31) STAGE_LOAD(it + 1);
    const char* Ks = lds + wk * 32768 + cur * 16384;
    const char* Vs = Ks + 8192;

    // S^T = K_perm @ Q (K fragment shared by both qh)
    f32x4 s[2][4] = {};
    __builtin_amdgcn_s_setprio(1);
#pragma unroll
    for (int t = 0; t < 4; ++t) {
      int krow = (t & 1) * 32 + ((llo >> 2) << 3) + ((t >> 1) << 2) + (llo & 3);
      int ksz = swz16(krow);
      const char* kp = Ks + krow * 128;
      bf16x8 k0 = *(const bf16x8*)(kp + ((lhi * 16) ^ ksz));
      bf16x8 k1 = *(const bf16x8*)(kp + ((64 + lhi * 16) ^ ksz));
      s[0][t] = MFMA16(k0, qf[0][0], s[0][t]);
      s[0][t] = MFMA16(k1, qf[0][1], s[0][t]);
      s[1][t] = MFMA16(k0, qf[1][0], s[1][t]);
      s[1][t] = MFMA16(k1, qf[1][1], s[1][t]);
    }
    __builtin_amdgcn_s_setprio(0);

    // online softmax per qh (lane owns one q per qh)
    union { unsigned int u[4]; bf16x8 v; } F0[2], F1[2];
#pragma unroll
    for (int qh = 0; qh < 2; ++qh) {
      float t0 = fmaxf(fmaxf(s[qh][0][0], s[qh][0][1]), fmaxf(s[qh][0][2], s[qh][0][3]));
      float t1 = fmaxf(fmaxf(s[qh][1][0], s[qh][1][1]), fmaxf(s[qh][1][2], s[qh][1][3]));
      float t2 = fmaxf(fmaxf(s[qh][2][0], s[qh][2][1]), fmaxf(s[qh][2][2], s[qh][2][3]));
      float t3 = fmaxf(fmaxf(s[qh][3][0], s[qh][3][1]), fmaxf(s[qh][3][2], s[qh][3][3]));
      float pm = fmaxf(fmaxf(t0, t1), fmaxf(t2, t3));
      pm = fmaxf(pm, __shfl_xor(pm, 16));
      pm = fmaxf(pm, __shfl_xor(pm, 32));
      if (__any(pm > m[qh])) {   // exact skip: pm<=m everywhere => al==1
        float mn = fmaxf(m[qh], pm);
        float al = __expf(m[qh] - mn);
        m[qh] = mn;
        lsum[qh] *= al;
#pragma unroll
        for (int dt = 0; dt < 4; ++dt)
#pragma unroll
          for (int r = 0; r < 4; ++r) oacc[qh][dt][r] *= al;
      }
#pragma unroll
      for (int t = 0; t < 4; ++t)
#pragma unroll
        for (int r = 0; r < 4; ++r) s[qh][t][r] = __expf(s[qh][t][r] - m[qh]);
      float p0 = (s[qh][0][0] + s[qh][0][1]) + (s[qh][0][2] + s[qh][0][3]);
      float p1 = (s[qh][1][0] + s[qh][1][1]) + (s[qh][1][2] + s[qh][1][3]);
      float p2 = (s[qh][2][0] + s[qh][2][1]) + (s[qh][2][2] + s[qh][2][3]);
      float p3 = (s[qh][3][0] + s[qh][3][1]) + (s[qh][3][2] + s[qh][3][3]);
      lsum[qh] += (p0 + p1) + (p2 + p3);

      F0[qh].u[0] = pk2(s[qh][0][0], s[qh][0][1]); F0[qh].u[1] = pk2(s[qh][0][2], s[qh][0][3]);
      F0[qh].u[2] = pk2(s[qh][2][0], s[qh][2][1]); F0[qh].u[3] = pk2(s[qh][2][2], s[qh][2][3]);
      F1[qh].u[0] = pk2(s[qh][1][0], s[qh][1][1]); F1[qh].u[1] = pk2(s[qh][1][2], s[qh][1][3]);
      F1[qh].u[2] = pk2(s[qh][3][0], s[qh][3][1]); F1[qh].u[3] = pk2(s[qh][3][2], s[qh][3][3]);
    }

    // O^T += V^T @ P^T (V fragment shared by both qh)
    __builtin_amdgcn_s_setprio(1);
#pragma unroll
    for (int dt = 0; dt < 4; ++dt) {
      int vrow = dt * 16 + llo;
      int vsz = swz16(vrow);
      const char* vp = Vs + vrow * 128;
      bf16x8 v0 = *(const bf16x8*)(vp + ((lhi * 16) ^ vsz));
      bf16x8 v1 = *(const bf16x8*)(vp + ((64 + lhi * 16) ^ vsz));
      oacc[0][dt] = MFMA16(v0, F0[0].v, oacc[0][dt]);
      oacc[0][dt] = MFMA16(v1, F1[0].v, oacc[0][dt]);
      oacc[1][dt] = MFMA16(v0, F0[1].v, oacc[1][dt]);
      oacc[1][dt] = MFMA16(v1, F1[1].v, oacc[1][dt]);
    }
    __builtin_amdgcn_s_setprio(0);

    if (it < 31) STAGE_WRITE(cur ^ 1);
    __syncthreads();
    cur ^= 1;
  }

  // full row sums across the 4 lanes sharing each q
#pragma unroll
  for (int qh = 0; qh < 2; ++qh) {
    lsum[qh] += __shfl_xor(lsum[qh], 16);
    lsum[qh] += __shfl_xor(lsum[qh], 32);
  }

  // merge the two k-halves via LDS (stride 65 kills bank conflicts)
  float* mO = (float*)lds;               // [64 q][65]
  float* mM = (float*)lds + 64 * 65;     // [64]
  float* mL = mM + 64;
  if (wk == 1) {
#pragma unroll
    for (int qh = 0; qh < 2; ++qh) {
      int ql = wq * 32 + qh * 16 + llo;
#pragma unroll
      for (int dt = 0; dt < 4; ++dt)
#pragma unroll
        for (int r = 0; r < 4; ++r)
          mO[ql * 65 + dt * 16 + lhi * 4 + r] = oacc[qh][dt][r];
      if (lhi == 0) { mM[ql] = m[qh]; mL[ql] = lsum[qh]; }
    }
  }
  __syncthreads();
  if (wk == 0) {
#pragma unroll
    for (int qh = 0; qh < 2; ++qh) {
      int ql = wq * 32 + qh * 16 + llo;
      float m2 = mM[ql], l2 = mL[ql];
      float mf = fmaxf(m[qh], m2);
      float e1 = __expf(m[qh] - mf);
      float e2 = __expf(m2 - mf);
      float inv = 1.f / (lsum[qh] * e1 + l2 * e2);
      int qglob = qt * 64 + ql;
      unsigned int* dst = (unsigned int*)(Ob + ((size_t)b * NN + qglob) * 128 + a * 64);
      const float* mOr = mO + ql * 65;
#pragma unroll
      for (int dt = 0; dt < 4; ++dt) {
        int d0 = dt * 16 + lhi * 4;
        float v0 = (oacc[qh][dt][0] * e1 + mOr[d0 + 0] * e2) * inv;
        float v1 = (oacc[qh][dt][1] * e1 + mOr[d0 + 1] * e2) * inv;
        float v2 = (oacc[qh][dt][2] * e1 + mOr[d0 + 2] * e2) * inv;
        float v3 = (oacc[qh][dt][3] * e1 + mOr[d0 + 3] * e2) * inv;
        dst[dt * 8 + lhi * 2] = pk2(v0, v1);
        dst[dt * 8 + lhi * 2 + 1] = pk2(v2, v3);
      }
    }
  }
}

// ---------------------------------------------------------------------------
// Kernel 5: OUT[b,c,n] = sum_d WO[c,d]*O[b,n,d] + BO[c] + x[b,c,n]
// ---------------------------------------------------------------------------
__global__ __launch_bounds__(256) void out_kernel(
    const unsigned short* __restrict__ Ob, const unsigned short* __restrict__ WO,
    const float* __restrict__ BO, const float* __restrict__ x,
    float* __restrict__ out)
{
  int nt = blockIdx.x;
  int ct = blockIdx.y;
  int b = blockIdx.z;
  int w = threadIdx.x >> 6, lane = threadIdx.x & 63;
  int lhi = lane >> 4, llo = lane & 15;
  int cb = ct * 64 + w * 16;

  f32x4 acc[4] = {};
#pragma unroll
  for (int kc = 0; kc < 4; ++kc) {
    bf16x8 af = *(const bf16x8*)(WO + (size_t)(cb + llo) * 128 + kc * 32 + lhi * 8);
#pragma unroll
    for (int nn = 0; nn < 4; ++nn) {
      bf16x8 bfr = *(const bf16x8*)(Ob + ((size_t)b * NN + nt * 64 + nn * 16 + llo) * 128 + kc * 32 + lhi * 8);
      acc[nn] = MFMA16(af, bfr, acc[nn]);
    }
  }
#pragma unroll
  for (int nn = 0; nn < 4; ++nn)
#pragma unroll
    for (int r = 0; r < 4; ++r) {
      int c = cb + lhi * 4 + r;
      int n = nt * 64 + nn * 16 + llo;
      size_t idx = ((size_t)b * CC + c) * NN + n;
      out[idx] = acc[nn][r] + BO[c] + x[idx];
    }
}

// ---------------------------------------------------------------------------
extern "C" void kernel_launch(void* const* d_in, const int* in_sizes, int n_in,
                              void* d_out, int out_size, void* d_ws, size_t ws_size,
                              hipStream_t stream) {
  const float* x = (const float*)d_in[0];
  const float* x1 = (const float*)d_in[1];
  const float* x2 = (const float*)d_in[2];
  const float* bn1_g = (const float*)d_in[3];
  const float* bn1_b = (const float*)d_in[4];
  const float* bn1_m = (const float*)d_in[5];
  const float* bn1_v = (const float*)d_in[6];
  const float* bn2_g = (const float*)d_in[7];
  const float* bn2_b = (const float*)d_in[8];
  const float* bn2_m = (const float*)d_in[9];
  const float* bn2_v = (const float*)d_in[10];
  const float* kq1_w = (const float*)d_in[11];
  const float* kq1_b = (const float*)d_in[12];
  const float* kq2_w = (const float*)d_in[13];
  const float* kq2_b = (const float*)d_in[14];
  const float* v_w = (const float*)d_in[15];
  const float* v_b = (const float*)d_in[16];
  const float* out_w = (const float*)d_in[17];
  const float* out_b = (const float*)d_in[18];
  const float* bnl_g = (const float*)d_in[19];
  const float* bnl_b = (const float*)d_in[20];
  const float* bnl_m = (const float*)d_in[21];
  const float* bnl_v = (const float*)d_in[22];
  const float* w_scale = (const float*)d_in[23];

  char* ws = (char*)d_ws;
  const size_t XT_SZ = (size_t)NB * NN * CC * 2;        // 8 MB each
  const size_t QKV_SZ = (size_t)NB * 2 * NN * DD * 2;   // 4 MB each
  size_t off = 0;
  unsigned short* XT0 = (unsigned short*)(ws + off); off += XT_SZ;
  unsigned short* XT1 = (unsigned short*)(ws + off); off += XT_SZ;
  unsigned short* XT2 = (unsigned short*)(ws + off); off += XT_SZ;
  unsigned short* Qb = (unsigned short*)(ws + off); off += QKV_SZ;
  unsigned short* Kb = (unsigned short*)(ws + off); off += QKV_SZ;
  unsigned short* Vt = (unsigned short*)(ws + off); off += QKV_SZ;
  unsigned short* Ob = (unsigned short*)(ws + off); off += (size_t)NB * NN * 128 * 2;
  unsigned short* W1 = (unsigned short*)(ws + off); off += 128 * CC * 2;
  unsigned short* W2 = (unsigned short*)(ws + off); off += 128 * CC * 2;
  unsigned short* WV = (unsigned short*)(ws + off); off += 128 * CC * 2;
  unsigned short* WO = (unsigned short*)(ws + off); off += CC * 128 * 2;
  float* B1 = (float*)(ws + off); off += 512;
  float* B2 = (float*)(ws + off); off += 512;
  float* BV = (float*)(ws + off); off += 512;
  float* BO = (float*)(ws + off); off += 1024;
  if (ws_size < off) return;  // loud failure: output stays poisoned

  prep_kernel<<<4, 256, 0, stream>>>(
      kq1_w, kq1_b, kq2_w, kq2_b, v_w, v_b, out_w, out_b,
      bn1_g, bn1_b, bn1_m, bn1_v, bn2_g, bn2_b, bn2_m, bn2_v,
      bnl_g, bnl_b, bnl_m, bnl_v, w_scale,
      W1, W2, WV, WO, B1, B2, BV, BO);

  conv_kernel<<<dim3(64, 4, 12), 256, 0, stream>>>(x, x1, x2, XT0, XT1, XT2);

  proj_kernel<<<dim3(64, 3, 4), 256, 0, stream>>>(
      XT0, XT1, XT2, W1, W2, WV, B1, B2, BV, Qb, Kb, Vt);

  attn_kernel<<<dim3(64, 2, 4), 256, 0, stream>>>(Qb, Kb, Vt, Ob);

  out_kernel<<<dim3(64, 4, 4), 256, 0, stream>>>(Ob, WO, BO, x, (float*)d_out);
}